// Round 1
// baseline (611.656 us; speedup 1.0000x reference)
//
#include <hip/hip_runtime.h>
#include <math.h>

#define B_DIM 4096
#define S_DIM 200
#define E_DIM 100
#define C_DIM 20
#define K_DIM 51
#define PADW  25

typedef _Float16 f16x8 __attribute__((ext_vector_type(8)));
typedef float    f32x4 __attribute__((ext_vector_type(4)));

// gT: 250 rows x 128B (img0 64B | img1 64B), XOR-swizzled in 16B groups by
// (row & 7) to break the stride-128 bank alignment.  Rows >= 250 only feed
// discarded outputs s' >= 200 (OOB LDS reads are harmless, same as before).
// Total LDS 32000 + 400 (ushort toks) = 32400 <= 32768 -> 5 blocks/CU.
#define GT_ROWS   250
#define GT_STRIDE 128
#define GT_BYTES  (GT_ROWS * GT_STRIDE)   // 32000
#define NA_FRAGS  (K_DIM*2*2)    // (k, img, mt)
#define NA_SHORTS (NA_FRAGS*512) // 104448

// ---------------------------------------------------------------------------
// Prep (verified r6/r7): packed-K A-fragments (fp16 split x256, MFMA lane
// order); Lt[e*20+c]; rnl[c].
//   img0 K-col r: r<20 -> a_hi[i=r] ; r>=20 -> a_lo[i=r-20]
//   img1 K-col r: r<8  -> a_lo[i=12+r]; 8<=r<28 -> a_hi[i=r-8]; else 0
// ---------------------------------------------------------------------------
__global__ void prep_kernel(const float* __restrict__ conv_w,
                            const float* __restrict__ labels,
                            short* __restrict__ wA,
                            float* __restrict__ Lt,
                            float* __restrict__ rnl) {
    int idx = blockIdx.x * 256 + threadIdx.x;
    if (idx < NA_SHORTS) {
        int frag = idx >> 9;           // ((k*2+img)*2+mt)
        int r    = idx & 511;
        int lane = r >> 3;
        int j    = r & 7;
        int mt   = frag & 1;
        int img  = (frag >> 1) & 1;
        int k    = frag >> 2;
        int o  = mt * 16 + (lane & 15);
        int kc = (lane >> 4) * 8 + j;  // K-col 0..31

        int i = -1, lo = 0;
        if (img == 0) {
            if (kc < 20) { i = kc;      lo = 0; }
            else         { i = kc - 20; lo = 1; }
        } else {
            if (kc < 8)       { i = 12 + kc; lo = 1; }
            else if (kc < 28) { i = kc - 8;  lo = 0; }
        }
        float v = 0.f;
        if (o < C_DIM && i >= 0) v = conv_w[(o * C_DIM + i) * K_DIM + k] * 256.f;
        _Float16 hi  = (_Float16)v;
        _Float16 val = lo ? (_Float16)(v - (float)hi) : hi;
        unsigned short bits;
        __builtin_memcpy(&bits, &val, 2);
        wA[idx] = (short)bits;
    } else if (idx < NA_SHORTS + C_DIM * E_DIM) {
        int t = idx - NA_SHORTS;
        int e = t / C_DIM, c = t % C_DIM;
        Lt[t] = labels[c * E_DIM + e];
    } else if (idx < NA_SHORTS + C_DIM * E_DIM + C_DIM) {
        int c = idx - NA_SHORTS - C_DIM * E_DIM;
        float s = 0.f;
        for (int e = 0; e < E_DIM; ++e) { float v = labels[c * E_DIM + e]; s += v * v; }
        float nn = sqrtf(s);
        rnl[c] = (nn > 0.f) ? 1.f / nn : 0.f;
    }
}

// ---------------------------------------------------------------------------
// Phase-ring conv: k = p + 16j.  B-frag for (tile t, k) depends only on
// f = t*16 + k, so per phase p a ring of CNT+3 fragments (registers) serves
// all (t,j); MFMA (t,j) uses ring[t+j].  Two K-images as separate passes.
// Rows are stride-128 with a 16B-group XOR swizzle by (row&7); since
// row = nt0*16 + n + p + 16d, (row&7) = (n+p)&7 -- constant across d.
// ---------------------------------------------------------------------------
template <int CNT>
__device__ __forceinline__ void conv_tiles(const short* __restrict__ wA,
                                           const char* rowbase,   // gT + (nt0*16+n)*GT_STRIDE
                                           f32x4 (&acc)[4][2],
                                           int lane) {
    const int n = lane & 15;
    const int q = lane >> 4;
#define LDFRAG(k, img, mt) (*(const f16x8*)(wA + (((k) * 2 + (img)) * 2 + (mt)) * 512 + lane * 8))
#pragma unroll
    for (int img = 0; img < 2; ++img) {
#pragma unroll 1
        for (int p = 0; p < 16; ++p) {
            // A-frags for this phase (k = p+16j), loaded up front
            f16x8 a0[4], a1[4];
#pragma unroll
            for (int j = 0; j < 4; ++j) {
                const int k = p + 16 * j;
                if (k < K_DIM) { a0[j] = LDFRAG(k, img, 0); a1[j] = LDFRAG(k, img, 1); }
            }
            // fragment ring (swizzled byte offset within the row)
            const int off = (q * 16 + img * 64) ^ (((n + p) & 7) << 4);
            const char* rp = rowbase + p * GT_STRIDE + off;
            f16x8 ring[CNT + 3];
            const int nd = (p < 3) ? (CNT + 3) : (CNT + 2);
#pragma unroll
            for (int d = 0; d < CNT + 3; ++d) {
                if (d < nd)
                    ring[d] = *(const f16x8*)(rp + d * 16 * GT_STRIDE);
            }
#pragma unroll
            for (int j = 0; j < 4; ++j) {
                if (p + 16 * j < K_DIM) {
#pragma unroll
                    for (int t = 0; t < CNT; ++t) {
                        acc[t][0] = __builtin_amdgcn_mfma_f32_16x16x32_f16(a0[j], ring[t + j], acc[t][0], 0, 0, 0);
                        acc[t][1] = __builtin_amdgcn_mfma_f32_16x16x32_f16(a1[j], ring[t + j], acc[t][1], 0, 0, 0);
                    }
                }
            }
        }
    }
#undef LDFRAG
}

// ---------------------------------------------------------------------------
// 256 threads (4 waves) per batch row.  Shared gT image; waves split n-tiles.
// __launch_bounds__(256,5): 5 blocks/CU (LDS 32400 fits) and VGPR cap 102 so
// the ring + batched a-frags + acc (~92 regs) stay live without streaming.
// ---------------------------------------------------------------------------
__launch_bounds__(256, 5)
__global__ void fused_kernel(const int* __restrict__ x,
                             const int* __restrict__ mask,     // bool -> int32
                             const float* __restrict__ emb,
                             const float* __restrict__ conv_b,
                             const float* __restrict__ w1,
                             const float* __restrict__ b1,
                             const float* __restrict__ w2,
                             const float* __restrict__ b2,
                             const short* __restrict__ wA,
                             const float* __restrict__ Lt,
                             const float* __restrict__ rnl,
                             float* __restrict__ out) {
    __shared__ __align__(16) char smem[GT_BYTES];   // gT, later aliased
    __shared__ unsigned short toks[S_DIM];

    short* gT   = (short*)smem;
    float* marr = (float*)(smem);            // [0,    800)   after conv
    float* red  = (float*)(smem + 1024);     // cross-wave scratch (8 floats)
    float* bw   = (float*)(smem + 2048);     // [2048, 2848)
    float* zp   = (float*)(smem + 3072);     // 4 x 100
    float* zsh  = (float*)(smem + 4672);
    float* hsh  = (float*)(smem + 5120);

    const int tid  = threadIdx.x;
    const int b    = blockIdx.x;
    const int lane = tid & 63;
    const int wv   = tid >> 6;
    const int n    = lane & 15;

    // ---- zero gT ----
    {
        float4 z{0.f, 0.f, 0.f, 0.f};
        float4* g4 = (float4*)gT;
        for (int j = tid; j < GT_BYTES / 16; j += 256) g4[j] = z;
    }

    const int s    = tid;
    const bool act = (s < S_DIM);
    int tok = 0, msk = 0;
    if (act) {
        tok = x[b * S_DIM + s];
        msk = mask[b * S_DIM + s];
        toks[s] = (unsigned short)tok;
    }
    __syncthreads();

    // ---- phase 1: cosine sims -> gT (split f16, packed-K images) ----
    if (act) {
        float dacc[C_DIM];
#pragma unroll
        for (int c = 0; c < C_DIM; ++c) dacc[c] = 0.f;
        float n2 = 0.f;
        const float4* er  = (const float4*)(emb + (size_t)tok * E_DIM);
        const float4* Lt4 = (const float4*)Lt;
        for (int j = 0; j < 25; ++j) {
            const float4 r = er[j];
            n2 += r.x * r.x + r.y * r.y + r.z * r.z + r.w * r.w;
            const float rv[4] = {r.x, r.y, r.z, r.w};
#pragma unroll
            for (int u = 0; u < 4; ++u) {
#pragma unroll
                for (int qq = 0; qq < 5; ++qq) {
                    const float4 a = Lt4[(j * 4 + u) * 5 + qq];
                    dacc[qq * 4 + 0] += rv[u] * a.x;
                    dacc[qq * 4 + 1] += rv[u] * a.y;
                    dacc[qq * 4 + 2] += rv[u] * a.z;
                    dacc[qq * 4 + 3] += rv[u] * a.w;
                }
            }
        }
        const float xn    = sqrtf(n2);
        const float rxn16 = (xn > 0.f) ? 16.f / xn : 0.f;

        unsigned short gh[C_DIM], gl[C_DIM];
#pragma unroll
        for (int c = 0; c < C_DIM; ++c) {
            float a = dacc[c] * rnl[c] * rxn16;
            _Float16 h = (_Float16)a;
            _Float16 l = (_Float16)(a - (float)h);
            __builtin_memcpy(&gh[c], &h, 2);
            __builtin_memcpy(&gl[c], &l, 2);
        }
#define PK(a, b) ((unsigned)(a) | ((unsigned)(b) << 16))
        unsigned tv[32];
        // image 1: gh[0..19], gh[0..11]
#pragma unroll
        for (int d = 0; d < 10; ++d) tv[d] = PK(gh[2 * d], gh[2 * d + 1]);
#pragma unroll
        for (int d = 0; d < 6; ++d)  tv[10 + d] = PK(gh[2 * d], gh[2 * d + 1]);
        // image 2: gh[12..19], gl[0..19], 0, 0
#pragma unroll
        for (int d = 0; d < 4; ++d)  tv[16 + d] = PK(gh[12 + 2 * d], gh[13 + 2 * d]);
#pragma unroll
        for (int d = 0; d < 10; ++d) tv[20 + d] = PK(gl[2 * d], gl[2 * d + 1]);
        tv[30] = 0u; tv[31] = 0u;
#undef PK
        // swizzled 16B-group stores: group g -> g ^ (row&7)
        const int row = PADW + s;
        const int h8  = row & 7;
        uint4* rw = (uint4*)(smem + row * GT_STRIDE);
#pragma unroll
        for (int g = 0; g < 8; ++g) {
            uint4 v;
            v.x = tv[4 * g + 0]; v.y = tv[4 * g + 1];
            v.z = tv[4 * g + 2]; v.w = tv[4 * g + 3];
            rw[g ^ h8] = v;
        }
    }
    __syncthreads();

    // ---- conv: waves split the 13 n-tiles (4/3/3/3) ----
    f32x4 acc[4][2];
#pragma unroll
    for (int t = 0; t < 4; ++t) {
        acc[t][0] = f32x4{0.f, 0.f, 0.f, 0.f};
        acc[t][1] = f32x4{0.f, 0.f, 0.f, 0.f};
    }
    const int nt0 = (wv == 0) ? 0 : (1 + wv * 3);      // 0,4,7,10
    const int cnt = (wv == 0) ? 4 : 3;
    const char* rowbase = (const char*)gT + (nt0 * 16 + n) * GT_STRIDE;
    if (wv == 0) conv_tiles<4>(wA, rowbase, acc, lane);
    else         conv_tiles<3>(wA, rowbase, acc, lane);

    __syncthreads();   // gT dead; overlay becomes live

    // ---- epilogue: relu+bias+channel max -> marr[s] ----
    {
        const int q = lane >> 4;
        const float inv = 1.f / 4096.f;
        float cb0[4], cb1[4];
#pragma unroll
        for (int r = 0; r < 4; ++r) {
            cb0[r] = conv_b[4 * q + r];
            cb1[r] = (q == 0) ? conv_b[16 + r] : 0.f;
        }
        for (int t = 0; t < cnt; ++t) {
            float m = 0.f;   // relu floor
#pragma unroll
            for (int r = 0; r < 4; ++r) m = fmaxf(m, acc[t][0][r] * inv + cb0[r]);
            if (q == 0) {
#pragma unroll
                for (int r = 0; r < 4; ++r) m = fmaxf(m, acc[t][1][r] * inv + cb1[r]);
            }
            m = fmaxf(m, __shfl_xor(m, 16));
            m = fmaxf(m, __shfl_xor(m, 32));
            const int ss = (nt0 + t) * 16 + n;
            if (q == 0 && ss < S_DIM) marr[ss] = m;
        }
    }
    __syncthreads();

    // ---- softmax over s: wave shuffles + 4-slot cross-wave ----
    {
        float mval = act ? ((msk != 0) ? marr[s] : -1e13f) : -1e30f;
        float lm = mval;
#pragma unroll
        for (int off = 32; off > 0; off >>= 1) lm = fmaxf(lm, __shfl_xor(lm, off));
        if (lane == 0) red[wv] = lm;
        __syncthreads();
        const float gmax = fmaxf(fmaxf(red[0], red[1]), fmaxf(red[2], red[3]));
        const float p = act ? expf(mval - gmax) : 0.f;
        float ps = p;
#pragma unroll
        for (int off = 32; off > 0; off >>= 1) ps += __shfl_xor(ps, off);
        if (lane == 0) red[4 + wv] = ps;
        __syncthreads();
        const float gsum = (red[4] + red[5]) + (red[6] + red[7]);
        if (act) bw[s] = p / gsum;
    }
    __syncthreads();

    // ---- pooling: wave w sums s in [50w, 50w+50), 2-way unrolled ----
    {
        float za0 = 0.f, zb0 = 0.f, za1 = 0.f, zb1 = 0.f;
        const int s0 = wv * 50;
        for (int ss = s0; ss < s0 + 50; ss += 2) {
            const float  w0  = bw[ss];
            const float  w1v = bw[ss + 1];
            const float* r0 = emb + (size_t)toks[ss] * E_DIM;
            const float* r1 = emb + (size_t)toks[ss + 1] * E_DIM;
            za0 += w0 * r0[lane];
            za1 += w1v * r1[lane];
            if (lane < E_DIM - 64) {
                zb0 += w0 * r0[64 + lane];
                zb1 += w1v * r1[64 + lane];
            }
        }
        zp[wv * E_DIM + lane] = za0 + za1;
        if (lane < E_DIM - 64) zp[wv * E_DIM + 64 + lane] = zb0 + zb1;
    }
    __syncthreads();
    if (tid < E_DIM)
        zsh[tid] = zp[tid] + zp[E_DIM + tid] + zp[2 * E_DIM + tid] + zp[3 * E_DIM + tid];
    __syncthreads();

    // ---- MLP ----
    if (tid < E_DIM / 2) {
        float h = b1[tid];
        for (int e = 0; e < E_DIM; ++e) h += zsh[e] * w1[e * (E_DIM / 2) + tid];
        hsh[tid] = fmaxf(h, 0.f);
    }
    __syncthreads();
    if (tid < C_DIM) {
        float o = b2[tid];
#pragma unroll
        for (int j = 0; j < E_DIM / 2; ++j) o += hsh[j] * w2[j * C_DIM + tid];
        out[b * C_DIM + tid] = o;
    }
}

// ---------------------------------------------------------------------------
extern "C" void kernel_launch(void* const* d_in, const int* in_sizes, int n_in,
                              void* d_out, int out_size, void* d_ws, size_t ws_size,
                              hipStream_t stream) {
    const int*   x      = (const int*)d_in[0];
    const int*   mask   = (const int*)d_in[2];    // bool delivered as int32
    const float* emb    = (const float*)d_in[3];
    const float* labels = (const float*)d_in[4];
    const float* conv_w = (const float*)d_in[5];
    const float* conv_b = (const float*)d_in[6];
    const float* w1     = (const float*)d_in[7];
    const float* b1     = (const float*)d_in[8];
    const float* w2     = (const float*)d_in[9];
    const float* b2     = (const float*)d_in[10];
    float*       out    = (float*)d_out;

    short* wA  = (short*)d_ws;                              // 208896 B
    float* Lt  = (float*)((char*)d_ws + NA_SHORTS * 2);     // 2000 floats
    float* rnl = Lt + C_DIM * E_DIM;                        // 20 floats

    const int prep_n = NA_SHORTS + C_DIM * E_DIM + C_DIM;
    prep_kernel<<<(prep_n + 255) / 256, 256, 0, stream>>>(conv_w, labels, wA, Lt, rnl);
    fused_kernel<<<B_DIM, 256, 0, stream>>>(x, mask, emb, conv_b,
                                            w1, b1, w2, b2, wA, Lt, rnl, out);
}

// Round 2
// 410.297 us; speedup vs baseline: 1.4908x; 1.4908x over previous
//
#include <hip/hip_runtime.h>
#include <math.h>

#define B_DIM 4096
#define S_DIM 200
#define E_DIM 100
#define C_DIM 20
#define K_DIM 51
#define PADW  25

typedef _Float16 f16x8 __attribute__((ext_vector_type(8)));
typedef float    f32x4 __attribute__((ext_vector_type(4)));

// gT: 250 rows x 128B (img0 64B | img1 64B), XOR-swizzled in 16B groups by
// (row & 7) to break the stride-128 bank alignment (round-1: conflicts -> 0).
// Rows >= 250 only feed discarded output columns (s' >= 200); slight
// past-the-end LDS reads feed only discarded columns too (verified r1).
#define GT_ROWS   250
#define GT_STRIDE 128
#define GT_BYTES  (GT_ROWS * GT_STRIDE)   // 32000
#define NA_FRAGS  (K_DIM*2*2)    // (k, img, mt)
#define NA_SHORTS (NA_FRAGS*512) // 104448

// ---------------------------------------------------------------------------
// Prep (verified r6/r7): packed-K A-fragments (fp16 split x256, MFMA lane
// order); Lt[e*20+c]; rnl[c].
//   img0 K-col r: r<20 -> a_hi[i=r] ; r>=20 -> a_lo[i=r-20]
//   img1 K-col r: r<8  -> a_lo[i=12+r]; 8<=r<28 -> a_hi[i=r-8]; else 0
// ---------------------------------------------------------------------------
__global__ void prep_kernel(const float* __restrict__ conv_w,
                            const float* __restrict__ labels,
                            short* __restrict__ wA,
                            float* __restrict__ Lt,
                            float* __restrict__ rnl) {
    int idx = blockIdx.x * 256 + threadIdx.x;
    if (idx < NA_SHORTS) {
        int frag = idx >> 9;           // ((k*2+img)*2+mt)
        int r    = idx & 511;
        int lane = r >> 3;
        int j    = r & 7;
        int mt   = frag & 1;
        int img  = (frag >> 1) & 1;
        int k    = frag >> 2;
        int o  = mt * 16 + (lane & 15);
        int kc = (lane >> 4) * 8 + j;  // K-col 0..31

        int i = -1, lo = 0;
        if (img == 0) {
            if (kc < 20) { i = kc;      lo = 0; }
            else         { i = kc - 20; lo = 1; }
        } else {
            if (kc < 8)       { i = 12 + kc; lo = 1; }
            else if (kc < 28) { i = kc - 8;  lo = 0; }
        }
        float v = 0.f;
        if (o < C_DIM && i >= 0) v = conv_w[(o * C_DIM + i) * K_DIM + k] * 256.f;
        _Float16 hi  = (_Float16)v;
        _Float16 val = lo ? (_Float16)(v - (float)hi) : hi;
        unsigned short bits;
        __builtin_memcpy(&bits, &val, 2);
        wA[idx] = (short)bits;
    } else if (idx < NA_SHORTS + C_DIM * E_DIM) {
        int t = idx - NA_SHORTS;
        int e = t / C_DIM, c = t % C_DIM;
        Lt[t] = labels[c * E_DIM + e];
    } else if (idx < NA_SHORTS + C_DIM * E_DIM + C_DIM) {
        int c = idx - NA_SHORTS - C_DIM * E_DIM;
        float s = 0.f;
        for (int e = 0; e < E_DIM; ++e) { float v = labels[c * E_DIM + e]; s += v * v; }
        float nn = sqrtf(s);
        rnl[c] = (nn > 0.f) ? 1.f / nn : 0.f;
    }
}

// ---------------------------------------------------------------------------
// Phase-ring conv, K-split: this wave handles j in {J0, J0+1} (k = p+16j)
// for CNT tiles.  Ring slot i (0..CNT) holds row p + 16*(J0+i); MFMA (t,j)
// uses slot t + (j-J0).  J0=0: both j always valid.  J0=2: j=3 valid iff
// p<3 (k=p+48<51); slot CNT is only consumed by (t=CNT-1, j=J0+1).
// All 4 A-frag loads for a phase are issued up-front (one L2 latency
// exposure per phase); MFMA:A-load ratio = CNT (~7) vs 3.25 before.
// ---------------------------------------------------------------------------
template <int CNT, int J0>
__device__ __forceinline__ void conv_ksplit(const short* __restrict__ wA,
                                            const char* rowbase,   // gT + (tg*16+n)*GT_STRIDE
                                            f32x4 (&acc)[7][2],
                                            int lane) {
    const int n = lane & 15;
    const int q = lane >> 4;
#define LDFRAG(k, img, mt) (*(const f16x8*)(wA + (((k) * 2 + (img)) * 2 + (mt)) * 512 + lane * 8))
#pragma unroll
    for (int img = 0; img < 2; ++img) {
#pragma unroll 1
        for (int p = 0; p < 16; ++p) {
            const bool j1ok = (J0 == 0) || (p < 3);
            // batched A-frags for this phase
            f16x8 a0[2], a1[2];
            a0[0] = LDFRAG(p + 16 * J0, img, 0);
            a1[0] = LDFRAG(p + 16 * J0, img, 1);
            if (j1ok) {
                a0[1] = LDFRAG(p + 16 * (J0 + 1), img, 0);
                a1[1] = LDFRAG(p + 16 * (J0 + 1), img, 1);
            }
            // fragment ring (swizzled byte offset within the row; row&7 is
            // (n+p)&7 since tg*16 + 16*(J0+i) = 0 mod 8)
            const int off = (q * 16 + img * 64) ^ (((n + p) & 7) << 4);
            const char* rp = rowbase + (p + 16 * J0) * GT_STRIDE + off;
            f16x8 ring[CNT + 1];
#pragma unroll
            for (int i = 0; i <= CNT; ++i) {
                if (i < CNT || j1ok)
                    ring[i] = *(const f16x8*)(rp + i * 16 * GT_STRIDE);
            }
#pragma unroll
            for (int t = 0; t < CNT; ++t) {
                acc[t][0] = __builtin_amdgcn_mfma_f32_16x16x32_f16(a0[0], ring[t], acc[t][0], 0, 0, 0);
                acc[t][1] = __builtin_amdgcn_mfma_f32_16x16x32_f16(a1[0], ring[t], acc[t][1], 0, 0, 0);
            }
            if (j1ok) {
#pragma unroll
                for (int t = 0; t < CNT; ++t) {
                    acc[t][0] = __builtin_amdgcn_mfma_f32_16x16x32_f16(a0[1], ring[t + 1], acc[t][0], 0, 0, 0);
                    acc[t][1] = __builtin_amdgcn_mfma_f32_16x16x32_f16(a1[1], ring[t + 1], acc[t][1], 0, 0, 0);
                }
            }
        }
    }
#undef LDFRAG
}

// ---------------------------------------------------------------------------
// 256 threads (4 waves) per batch row.
//   wv0: tiles 0-6,  j{0,1}   wv1: tiles 7-12, j{0,1}
//   wv2: tiles 0-6,  j{2,3}   wv3: tiles 7-12, j{2,3}
// K-halves reduced via LDS partials (gT dead by then).
// __launch_bounds__(256,4): VGPR cap 64 (arch pool 256/EU — r1 showed 5
// waves forces 48 and spills), AGPR cap 64 holds acc (56).
// ---------------------------------------------------------------------------
__launch_bounds__(256, 4)
__global__ void fused_kernel(const int* __restrict__ x,
                             const int* __restrict__ mask,     // bool -> int32
                             const float* __restrict__ emb,
                             const float* __restrict__ conv_b,
                             const float* __restrict__ w1,
                             const float* __restrict__ b1,
                             const float* __restrict__ w2,
                             const float* __restrict__ b2,
                             const short* __restrict__ wA,
                             const float* __restrict__ Lt,
                             const float* __restrict__ rnl,
                             float* __restrict__ out) {
    __shared__ __align__(16) char smem[GT_BYTES];   // gT, later aliased
    __shared__ unsigned short toks[S_DIM];

    short* gT   = (short*)smem;
    float* marr = (float*)(smem);            // [0,    800)   after conv
    float* red  = (float*)(smem + 1024);     // cross-wave scratch (8 floats)
    float* bw   = (float*)(smem + 2048);     // [2048, 2848)
    float* zp   = (float*)(smem + 3072);     // 4 x 100
    float* zsh  = (float*)(smem + 4672);
    float* hsh  = (float*)(smem + 5120);
    float* part = (float*)(smem + 4096);     // K-half partials (26 KB), used
                                             // between conv and epilogue only

    const int tid  = threadIdx.x;
    const int b    = blockIdx.x;
    const int lane = tid & 63;
    const int wv   = tid >> 6;
    const int n    = lane & 15;

    // ---- zero gT ----
    {
        float4 z{0.f, 0.f, 0.f, 0.f};
        float4* g4 = (float4*)gT;
        for (int j = tid; j < GT_BYTES / 16; j += 256) g4[j] = z;
    }

    const int s    = tid;
    const bool act = (s < S_DIM);
    int tok = 0, msk = 0;
    if (act) {
        tok = x[b * S_DIM + s];
        msk = mask[b * S_DIM + s];
        toks[s] = (unsigned short)tok;
    }
    __syncthreads();

    // ---- phase 1: cosine sims -> gT (split f16, packed-K images) ----
    if (act) {
        float dacc[C_DIM];
#pragma unroll
        for (int c = 0; c < C_DIM; ++c) dacc[c] = 0.f;
        float n2 = 0.f;
        const float4* er  = (const float4*)(emb + (size_t)tok * E_DIM);
        const float4* Lt4 = (const float4*)Lt;
        for (int j = 0; j < 25; ++j) {
            const float4 r = er[j];
            n2 += r.x * r.x + r.y * r.y + r.z * r.z + r.w * r.w;
            const float rv[4] = {r.x, r.y, r.z, r.w};
#pragma unroll
            for (int u = 0; u < 4; ++u) {
#pragma unroll
                for (int qq = 0; qq < 5; ++qq) {
                    const float4 a = Lt4[(j * 4 + u) * 5 + qq];
                    dacc[qq * 4 + 0] += rv[u] * a.x;
                    dacc[qq * 4 + 1] += rv[u] * a.y;
                    dacc[qq * 4 + 2] += rv[u] * a.z;
                    dacc[qq * 4 + 3] += rv[u] * a.w;
                }
            }
        }
        const float xn    = sqrtf(n2);
        const float rxn16 = (xn > 0.f) ? 16.f / xn : 0.f;

        unsigned short gh[C_DIM], gl[C_DIM];
#pragma unroll
        for (int c = 0; c < C_DIM; ++c) {
            float a = dacc[c] * rnl[c] * rxn16;
            _Float16 h = (_Float16)a;
            _Float16 l = (_Float16)(a - (float)h);
            __builtin_memcpy(&gh[c], &h, 2);
            __builtin_memcpy(&gl[c], &l, 2);
        }
        // swizzled 16B-group stores: group g -> g ^ (row&7)
        // word layout (img0 64B | img1 64B):
        //   w0-9: gh0..19 | w10-15: gh0..11 | w16-19: gh12..19 |
        //   w20-29: gl0..19 | w30,31: 0
        const int row = PADW + s;
        const int h8  = row & 7;
        uint4* rw = (uint4*)(smem + row * GT_STRIDE);
#define PK(a, b) ((unsigned)(a) | ((unsigned)(b) << 16))
        uint4 v;
        v.x = PK(gh[0], gh[1]);   v.y = PK(gh[2], gh[3]);
        v.z = PK(gh[4], gh[5]);   v.w = PK(gh[6], gh[7]);    rw[0 ^ h8] = v;
        v.x = PK(gh[8], gh[9]);   v.y = PK(gh[10], gh[11]);
        v.z = PK(gh[12], gh[13]); v.w = PK(gh[14], gh[15]);  rw[1 ^ h8] = v;
        v.x = PK(gh[16], gh[17]); v.y = PK(gh[18], gh[19]);
        v.z = PK(gh[0], gh[1]);   v.w = PK(gh[2], gh[3]);    rw[2 ^ h8] = v;
        v.x = PK(gh[4], gh[5]);   v.y = PK(gh[6], gh[7]);
        v.z = PK(gh[8], gh[9]);   v.w = PK(gh[10], gh[11]);  rw[3 ^ h8] = v;
        v.x = PK(gh[12], gh[13]); v.y = PK(gh[14], gh[15]);
        v.z = PK(gh[16], gh[17]); v.w = PK(gh[18], gh[19]);  rw[4 ^ h8] = v;
        v.x = PK(gl[0], gl[1]);   v.y = PK(gl[2], gl[3]);
        v.z = PK(gl[4], gl[5]);   v.w = PK(gl[6], gl[7]);    rw[5 ^ h8] = v;
        v.x = PK(gl[8], gl[9]);   v.y = PK(gl[10], gl[11]);
        v.z = PK(gl[12], gl[13]); v.w = PK(gl[14], gl[15]);  rw[6 ^ h8] = v;
        v.x = PK(gl[16], gl[17]); v.y = PK(gl[18], gl[19]);
        v.z = 0u;                 v.w = 0u;                  rw[7 ^ h8] = v;
#undef PK
    }
    __syncthreads();

    // ---- conv: tile-half x K-half wave split ----
    f32x4 acc[7][2];
#pragma unroll
    for (int t = 0; t < 7; ++t) {
        acc[t][0] = f32x4{0.f, 0.f, 0.f, 0.f};
        acc[t][1] = f32x4{0.f, 0.f, 0.f, 0.f};
    }
    const int tg = (wv & 1) ? 7 : 0;              // tile base (7 or 6 tiles)
    const char* rowbase = (const char*)gT + (tg * 16 + n) * GT_STRIDE;
    if      (wv == 0) conv_ksplit<7, 0>(wA, rowbase, acc, lane);
    else if (wv == 1) conv_ksplit<6, 0>(wA, rowbase, acc, lane);
    else if (wv == 2) conv_ksplit<7, 2>(wA, rowbase, acc, lane);
    else              conv_ksplit<6, 2>(wA, rowbase, acc, lane);

    __syncthreads();   // conv done; gT dead, partial overlay becomes live

    // ---- K-half reduction: waves 2,3 publish partials ----
    if (wv >= 2) {
        const int cnt2 = (wv == 3) ? 6 : 7;
        for (int t = 0; t < cnt2; ++t) {
#pragma unroll
            for (int mt = 0; mt < 2; ++mt)
                *(f32x4*)(part + (((tg + t) * 2 + mt) * 64 + lane) * 4) = acc[t][mt];
        }
    }
    __syncthreads();

    // ---- epilogue (waves 0,1): add partials, relu+bias+channel max ----
    if (wv < 2) {
        const int cnt2 = (wv == 1) ? 6 : 7;
        const int q = lane >> 4;
        const float inv = 1.f / 4096.f;
        float cb0[4], cb1[4];
#pragma unroll
        for (int r = 0; r < 4; ++r) {
            cb0[r] = conv_b[4 * q + r];
            cb1[r] = (q == 0) ? conv_b[16 + r] : 0.f;
        }
        for (int t = 0; t < cnt2; ++t) {
#pragma unroll
            for (int mt = 0; mt < 2; ++mt) {
                const f32x4 pv = *(const f32x4*)(part + (((tg + t) * 2 + mt) * 64 + lane) * 4);
                acc[t][mt] += pv;
            }
            float m = 0.f;   // relu floor
#pragma unroll
            for (int r = 0; r < 4; ++r) m = fmaxf(m, acc[t][0][r] * inv + cb0[r]);
            if (q == 0) {
#pragma unroll
                for (int r = 0; r < 4; ++r) m = fmaxf(m, acc[t][1][r] * inv + cb1[r]);
            }
            m = fmaxf(m, __shfl_xor(m, 16));
            m = fmaxf(m, __shfl_xor(m, 32));
            const int ss = (tg + t) * 16 + n;
            if (q == 0 && ss < S_DIM) marr[ss] = m;
        }
    }
    __syncthreads();

    // ---- softmax over s: wave shuffles + 4-slot cross-wave ----
    {
        float mval = act ? ((msk != 0) ? marr[s] : -1e13f) : -1e30f;
        float lm = mval;
#pragma unroll
        for (int off = 32; off > 0; off >>= 1) lm = fmaxf(lm, __shfl_xor(lm, off));
        if (lane == 0) red[wv] = lm;
        __syncthreads();
        const float gmax = fmaxf(fmaxf(red[0], red[1]), fmaxf(red[2], red[3]));
        const float p = act ? expf(mval - gmax) : 0.f;
        float ps = p;
#pragma unroll
        for (int off = 32; off > 0; off >>= 1) ps += __shfl_xor(ps, off);
        if (lane == 0) red[4 + wv] = ps;
        __syncthreads();
        const float gsum = (red[4] + red[5]) + (red[6] + red[7]);
        if (act) bw[s] = p / gsum;
    }
    __syncthreads();

    // ---- pooling: wave w sums s in [50w, 50w+50), 2-way unrolled ----
    {
        float za0 = 0.f, zb0 = 0.f, za1 = 0.f, zb1 = 0.f;
        const int s0 = wv * 50;
        for (int ss = s0; ss < s0 + 50; ss += 2) {
            const float  w0  = bw[ss];
            const float  w1v = bw[ss + 1];
            const float* r0 = emb + (size_t)toks[ss] * E_DIM;
            const float* r1 = emb + (size_t)toks[ss + 1] * E_DIM;
            za0 += w0 * r0[lane];
            za1 += w1v * r1[lane];
            if (lane < E_DIM - 64) {
                zb0 += w0 * r0[64 + lane];
                zb1 += w1v * r1[64 + lane];
            }
        }
        zp[wv * E_DIM + lane] = za0 + za1;
        if (lane < E_DIM - 64) zp[wv * E_DIM + 64 + lane] = zb0 + zb1;
    }
    __syncthreads();
    if (tid < E_DIM)
        zsh[tid] = zp[tid] + zp[E_DIM + tid] + zp[2 * E_DIM + tid] + zp[3 * E_DIM + tid];
    __syncthreads();

    // ---- MLP ----
    if (tid < E_DIM / 2) {
        float h = b1[tid];
        for (int e = 0; e < E_DIM; ++e) h += zsh[e] * w1[e * (E_DIM / 2) + tid];
        hsh[tid] = fmaxf(h, 0.f);
    }
    __syncthreads();
    if (tid < C_DIM) {
        float o = b2[tid];
#pragma unroll
        for (int j = 0; j < E_DIM / 2; ++j) o += hsh[j] * w2[j * C_DIM + tid];
        out[b * C_DIM + tid] = o;
    }
}

// ---------------------------------------------------------------------------
extern "C" void kernel_launch(void* const* d_in, const int* in_sizes, int n_in,
                              void* d_out, int out_size, void* d_ws, size_t ws_size,
                              hipStream_t stream) {
    const int*   x      = (const int*)d_in[0];
    const int*   mask   = (const int*)d_in[2];    // bool delivered as int32
    const float* emb    = (const float*)d_in[3];
    const float* labels = (const float*)d_in[4];
    const float* conv_w = (const float*)d_in[5];
    const float* conv_b = (const float*)d_in[6];
    const float* w1     = (const float*)d_in[7];
    const float* b1     = (const float*)d_in[8];
    const float* w2     = (const float*)d_in[9];
    const float* b2     = (const float*)d_in[10];
    float*       out    = (float*)d_out;

    short* wA  = (short*)d_ws;                              // 208896 B
    float* Lt  = (float*)((char*)d_ws + NA_SHORTS * 2);     // 2000 floats
    float* rnl = Lt + C_DIM * E_DIM;                        // 20 floats

    const int prep_n = NA_SHORTS + C_DIM * E_DIM + C_DIM;
    prep_kernel<<<(prep_n + 255) / 256, 256, 0, stream>>>(conv_w, labels, wA, Lt, rnl);
    fused_kernel<<<B_DIM, 256, 0, stream>>>(x, mask, emb, conv_b,
                                            w1, b1, w2, b2, wA, Lt, rnl, out);
}

// Round 3
// 348.585 us; speedup vs baseline: 1.7547x; 1.1770x over previous
//
#include <hip/hip_runtime.h>
#include <math.h>

#define B_DIM 4096
#define S_DIM 200
#define E_DIM 100
#define C_DIM 20
#define K_DIM 51
#define PADW  25

typedef _Float16 f16x8 __attribute__((ext_vector_type(8)));
typedef float    f32x4 __attribute__((ext_vector_type(4)));
typedef float    f32x2 __attribute__((ext_vector_type(2)));

// gT: 250 rows x 128B (img0 64B | img1 64B), XOR-swizzled in 16B groups by
// (row & 7) to break the stride-128 bank alignment (r1: conflicts 1.15e7->1e5,
// correctness verified).  Reads past row 250 feed only discarded output
// columns (s' >= 200) -- verified harmless in r0/r1.
#define GT_ROWS   250
#define GT_STRIDE 128
#define GT_BYTES  (GT_ROWS * GT_STRIDE)   // 32000
#define NA_FRAGS  (K_DIM*2*2)    // (k, img, mt)
#define NA_SHORTS (NA_FRAGS*512) // 104448

// ---------------------------------------------------------------------------
// Prep (verified r6/r7): packed-K A-fragments (fp16 split x256, MFMA lane
// order); Lt[e*20+c]; rnl[c].
//   img0 K-col r: r<20 -> a_hi[i=r] ; r>=20 -> a_lo[i=r-20]
//   img1 K-col r: r<8  -> a_lo[i=12+r]; 8<=r<28 -> a_hi[i=r-8]; else 0
// ---------------------------------------------------------------------------
__global__ void prep_kernel(const float* __restrict__ conv_w,
                            const float* __restrict__ labels,
                            short* __restrict__ wA,
                            float* __restrict__ Lt,
                            float* __restrict__ rnl) {
    int idx = blockIdx.x * 256 + threadIdx.x;
    if (idx < NA_SHORTS) {
        int frag = idx >> 9;           // ((k*2+img)*2+mt)
        int r    = idx & 511;
        int lane = r >> 3;
        int j    = r & 7;
        int mt   = frag & 1;
        int img  = (frag >> 1) & 1;
        int k    = frag >> 2;
        int o  = mt * 16 + (lane & 15);
        int kc = (lane >> 4) * 8 + j;  // K-col 0..31

        int i = -1, lo = 0;
        if (img == 0) {
            if (kc < 20) { i = kc;      lo = 0; }
            else         { i = kc - 20; lo = 1; }
        } else {
            if (kc < 8)       { i = 12 + kc; lo = 1; }
            else if (kc < 28) { i = kc - 8;  lo = 0; }
        }
        float v = 0.f;
        if (o < C_DIM && i >= 0) v = conv_w[(o * C_DIM + i) * K_DIM + k] * 256.f;
        _Float16 hi  = (_Float16)v;
        _Float16 val = lo ? (_Float16)(v - (float)hi) : hi;
        unsigned short bits;
        __builtin_memcpy(&bits, &val, 2);
        wA[idx] = (short)bits;
    } else if (idx < NA_SHORTS + C_DIM * E_DIM) {
        int t = idx - NA_SHORTS;
        int e = t / C_DIM, c = t % C_DIM;
        Lt[t] = labels[c * E_DIM + e];
    } else if (idx < NA_SHORTS + C_DIM * E_DIM + C_DIM) {
        int c = idx - NA_SHORTS - C_DIM * E_DIM;
        float s = 0.f;
        for (int e = 0; e < E_DIM; ++e) { float v = labels[c * E_DIM + e]; s += v * v; }
        float nn = sqrtf(s);
        rnl[c] = (nn > 0.f) ? 1.f / nn : 0.f;
    }
}

// ---------------------------------------------------------------------------
// Phase-ring conv (r0 structure, proven spill-free at 64 VGPR + 32 AGPR acc):
// k = p + 16j.  B-frag for (tile t, k) depends only on f = t*16 + k, so per
// phase p a ring of CNT+3 fragments (registers) serves all (t,j); MFMA (t,j)
// uses ring[t+j].  Two K-images as separate passes.
// Swizzled reads: row = nt0*16 + n + p + 16d -> (row&7) = (n+p)&7, constant
// across d, so one XOR per phase.
// ---------------------------------------------------------------------------
template <int CNT>
__device__ __forceinline__ void conv_tiles(const short* __restrict__ wA,
                                           const char* rowbase,   // gT + (nt0*16+n)*GT_STRIDE
                                           f32x4 (&acc)[4][2],
                                           int lane) {
    const int n = lane & 15;
    const int q = lane >> 4;
#define LDFRAG(k, img, mt) (*(const f16x8*)(wA + (((k) * 2 + (img)) * 2 + (mt)) * 512 + lane * 8))
#pragma unroll
    for (int img = 0; img < 2; ++img) {
#pragma unroll 1
        for (int p = 0; p < 16; ++p) {
            // A-frags for this phase (k = p+16j), loaded up front
            f16x8 a0[4], a1[4];
#pragma unroll
            for (int j = 0; j < 4; ++j) {
                const int k = p + 16 * j;
                if (k < K_DIM) { a0[j] = LDFRAG(k, img, 0); a1[j] = LDFRAG(k, img, 1); }
            }
            // fragment ring (swizzled byte offset within the row)
            const int off = (q * 16 + img * 64) ^ (((n + p) & 7) << 4);
            const char* rp = rowbase + p * GT_STRIDE + off;
            f16x8 ring[CNT + 3];
            const int nd = (p < 3) ? (CNT + 3) : (CNT + 2);
#pragma unroll
            for (int d = 0; d < CNT + 3; ++d) {
                if (d < nd)
                    ring[d] = *(const f16x8*)(rp + d * 16 * GT_STRIDE);
            }
#pragma unroll
            for (int j = 0; j < 4; ++j) {
                if (p + 16 * j < K_DIM) {
#pragma unroll
                    for (int t = 0; t < CNT; ++t) {
                        acc[t][0] = __builtin_amdgcn_mfma_f32_16x16x32_f16(a0[j], ring[t + j], acc[t][0], 0, 0, 0);
                        acc[t][1] = __builtin_amdgcn_mfma_f32_16x16x32_f16(a1[j], ring[t + j], acc[t][1], 0, 0, 0);
                    }
                }
            }
        }
    }
#undef LDFRAG
}

// ---------------------------------------------------------------------------
// 256 threads (4 waves) per batch row.  Shared gT image; waves split n-tiles
// 4/3/3/3.  __launch_bounds__(256,4): arch-VGPR cap 64 (r1 proved 5 waves/EU
// forces 48 and spills); acc lives in AGPRs (unified file, not LDS-capped).
// All acc indexing is compile-time (r2 lesson: runtime-bounded acc loops
// demote the array to scratch -> 445 MB of spill traffic).
// ---------------------------------------------------------------------------
__launch_bounds__(256, 4)
__global__ void fused_kernel(const int* __restrict__ x,
                             const int* __restrict__ mask,     // bool -> int32
                             const float* __restrict__ emb,
                             const float* __restrict__ conv_b,
                             const float* __restrict__ w1,
                             const float* __restrict__ b1,
                             const float* __restrict__ w2,
                             const float* __restrict__ b2,
                             const short* __restrict__ wA,
                             const float* __restrict__ Lt,
                             const float* __restrict__ rnl,
                             float* __restrict__ out) {
    __shared__ __align__(16) char smem[GT_BYTES];   // gT, later aliased
    __shared__ unsigned short toks[S_DIM];

    short* gT   = (short*)smem;
    float* marr = (float*)(smem);            // [0,    800)   after conv
    float* red  = (float*)(smem + 1024);     // cross-wave scratch (8 floats)
    float* bw   = (float*)(smem + 2048);     // [2048, 2848)
    float* zp   = (float*)(smem + 3072);     // 4 x 100
    float* zsh  = (float*)(smem + 4672);
    float* hsh  = (float*)(smem + 5120);

    const int tid  = threadIdx.x;
    const int b    = blockIdx.x;
    const int lane = tid & 63;
    const int wv   = tid >> 6;
    const int n    = lane & 15;

    // ---- zero gT ----
    {
        float4 z{0.f, 0.f, 0.f, 0.f};
        float4* g4 = (float4*)gT;
        for (int j = tid; j < GT_BYTES / 16; j += 256) g4[j] = z;
    }

    const int s    = tid;
    const bool act = (s < S_DIM);
    int tok = 0, msk = 0;
    if (act) {
        tok = x[b * S_DIM + s];
        msk = mask[b * S_DIM + s];
        toks[s] = (unsigned short)tok;
    }
    __syncthreads();

    // ---- phase 1: cosine sims -> gT (split f16, packed-K images) ----
    // Packed f32 dot: dacc2[i] = channels (2i, 2i+1); Lt row-major in e so
    // channel pairs are contiguous -> v_pk_fma_f32 (halves FMA issue count).
    if (act) {
        f32x2 dacc2[10];
#pragma unroll
        for (int i = 0; i < 10; ++i) dacc2[i] = f32x2{0.f, 0.f};
        float n2 = 0.f;
        const float4* er  = (const float4*)(emb + (size_t)tok * E_DIM);
        const f32x2* Lt2 = (const f32x2*)Lt;
        for (int j = 0; j < 25; ++j) {
            const float4 r = er[j];
            n2 += r.x * r.x + r.y * r.y + r.z * r.z + r.w * r.w;
            const float rv[4] = {r.x, r.y, r.z, r.w};
#pragma unroll
            for (int u = 0; u < 4; ++u) {
                const f32x2 xe = {rv[u], rv[u]};
                const f32x2* Lrow = Lt2 + (j * 4 + u) * 10;
#pragma unroll
                for (int i = 0; i < 10; ++i)
                    dacc2[i] += xe * Lrow[i];
            }
        }
        const float xn    = sqrtf(n2);
        const float rxn16 = (xn > 0.f) ? 16.f / xn : 0.f;

        unsigned short gh[C_DIM], gl[C_DIM];
#pragma unroll
        for (int c = 0; c < C_DIM; ++c) {
            float a = dacc2[c >> 1][c & 1] * rnl[c] * rxn16;
            _Float16 h = (_Float16)a;
            _Float16 l = (_Float16)(a - (float)h);
            __builtin_memcpy(&gh[c], &h, 2);
            __builtin_memcpy(&gl[c], &l, 2);
        }
#define PK(a, b) ((unsigned)(a) | ((unsigned)(b) << 16))
        unsigned tv[32];
        // image 1: gh[0..19], gh[0..11]
#pragma unroll
        for (int d = 0; d < 10; ++d) tv[d] = PK(gh[2 * d], gh[2 * d + 1]);
#pragma unroll
        for (int d = 0; d < 6; ++d)  tv[10 + d] = PK(gh[2 * d], gh[2 * d + 1]);
        // image 2: gh[12..19], gl[0..19], 0, 0
#pragma unroll
        for (int d = 0; d < 4; ++d)  tv[16 + d] = PK(gh[12 + 2 * d], gh[13 + 2 * d]);
#pragma unroll
        for (int d = 0; d < 10; ++d) tv[20 + d] = PK(gl[2 * d], gl[2 * d + 1]);
        tv[30] = 0u; tv[31] = 0u;
#undef PK
        // swizzled 16B-group stores: group g -> g ^ (row&7)
        const int row = PADW + s;
        const int h8  = row & 7;
        uint4* rw = (uint4*)(smem + row * GT_STRIDE);
#pragma unroll
        for (int g = 0; g < 8; ++g) {
            uint4 v;
            v.x = tv[4 * g + 0]; v.y = tv[4 * g + 1];
            v.z = tv[4 * g + 2]; v.w = tv[4 * g + 3];
            rw[g ^ h8] = v;
        }
    }
    __syncthreads();

    // ---- conv: waves split the 13 n-tiles (4/3/3/3) ----
    f32x4 acc[4][2];
#pragma unroll
    for (int t = 0; t < 4; ++t) {
        acc[t][0] = f32x4{0.f, 0.f, 0.f, 0.f};
        acc[t][1] = f32x4{0.f, 0.f, 0.f, 0.f};
    }
    const int nt0 = (wv == 0) ? 0 : (1 + wv * 3);      // 0,4,7,10
    const int cnt = (wv == 0) ? 4 : 3;
    const char* rowbase = (const char*)gT + (nt0 * 16 + n) * GT_STRIDE;
    if (wv == 0) conv_tiles<4>(wA, rowbase, acc, lane);
    else         conv_tiles<3>(wA, rowbase, acc, lane);

    __syncthreads();   // gT dead; overlay becomes live

    // ---- epilogue: relu+bias+channel max -> marr[s] (static t indexing) ----
    {
        const int q = lane >> 4;
        const float inv = 1.f / 4096.f;
        float cb0[4], cb1[4];
#pragma unroll
        for (int r = 0; r < 4; ++r) {
            cb0[r] = conv_b[4 * q + r];
            cb1[r] = (q == 0) ? conv_b[16 + r] : 0.f;
        }
#pragma unroll
        for (int t = 0; t < 4; ++t) {
            if (t < cnt) {
                float m = 0.f;   // relu floor
#pragma unroll
                for (int r = 0; r < 4; ++r) m = fmaxf(m, acc[t][0][r] * inv + cb0[r]);
                if (q == 0) {
#pragma unroll
                    for (int r = 0; r < 4; ++r) m = fmaxf(m, acc[t][1][r] * inv + cb1[r]);
                }
                m = fmaxf(m, __shfl_xor(m, 16));
                m = fmaxf(m, __shfl_xor(m, 32));
                const int ss = (nt0 + t) * 16 + n;
                if (q == 0 && ss < S_DIM) marr[ss] = m;
            }
        }
    }
    __syncthreads();

    // ---- softmax over s: wave shuffles + 4-slot cross-wave ----
    {
        float mval = act ? ((msk != 0) ? marr[s] : -1e13f) : -1e30f;
        float lm = mval;
#pragma unroll
        for (int off = 32; off > 0; off >>= 1) lm = fmaxf(lm, __shfl_xor(lm, off));
        if (lane == 0) red[wv] = lm;
        __syncthreads();
        const float gmax = fmaxf(fmaxf(red[0], red[1]), fmaxf(red[2], red[3]));
        const float p = act ? expf(mval - gmax) : 0.f;
        float ps = p;
#pragma unroll
        for (int off = 32; off > 0; off >>= 1) ps += __shfl_xor(ps, off);
        if (lane == 0) red[4 + wv] = ps;
        __syncthreads();
        const float gsum = (red[4] + red[5]) + (red[6] + red[7]);
        if (act) bw[s] = p / gsum;
    }
    __syncthreads();

    // ---- pooling: wave w sums s in [50w, 50w+50), 2-way unrolled ----
    {
        float za0 = 0.f, zb0 = 0.f, za1 = 0.f, zb1 = 0.f;
        const int s0 = wv * 50;
        for (int ss = s0; ss < s0 + 50; ss += 2) {
            const float  w0  = bw[ss];
            const float  w1v = bw[ss + 1];
            const float* r0 = emb + (size_t)toks[ss] * E_DIM;
            const float* r1 = emb + (size_t)toks[ss + 1] * E_DIM;
            za0 += w0 * r0[lane];
            za1 += w1v * r1[lane];
            if (lane < E_DIM - 64) {
                zb0 += w0 * r0[64 + lane];
                zb1 += w1v * r1[64 + lane];
            }
        }
        zp[wv * E_DIM + lane] = za0 + za1;
        if (lane < E_DIM - 64) zp[wv * E_DIM + 64 + lane] = zb0 + zb1;
    }
    __syncthreads();
    if (tid < E_DIM)
        zsh[tid] = zp[tid] + zp[E_DIM + tid] + zp[2 * E_DIM + tid] + zp[3 * E_DIM + tid];
    __syncthreads();

    // ---- MLP ----
    if (tid < E_DIM / 2) {
        float h = b1[tid];
        for (int e = 0; e < E_DIM; ++e) h += zsh[e] * w1[e * (E_DIM / 2) + tid];
        hsh[tid] = fmaxf(h, 0.f);
    }
    __syncthreads();
    if (tid < C_DIM) {
        float o = b2[tid];
#pragma unroll
        for (int j = 0; j < E_DIM / 2; ++j) o += hsh[j] * w2[j * C_DIM + tid];
        out[b * C_DIM + tid] = o;
    }
}

// ---------------------------------------------------------------------------
extern "C" void kernel_launch(void* const* d_in, const int* in_sizes, int n_in,
                              void* d_out, int out_size, void* d_ws, size_t ws_size,
                              hipStream_t stream) {
    const int*   x      = (const int*)d_in[0];
    const int*   mask   = (const int*)d_in[2];    // bool delivered as int32
    const float* emb    = (const float*)d_in[3];
    const float* labels = (const float*)d_in[4];
    const float* conv_w = (const float*)d_in[5];
    const float* conv_b = (const float*)d_in[6];
    const float* w1     = (const float*)d_in[7];
    const float* b1     = (const float*)d_in[8];
    const float* w2     = (const float*)d_in[9];
    const float* b2     = (const float*)d_in[10];
    float*       out    = (float*)d_out;

    short* wA  = (short*)d_ws;                              // 208896 B
    float* Lt  = (float*)((char*)d_ws + NA_SHORTS * 2);     // 2000 floats
    float* rnl = Lt + C_DIM * E_DIM;                        // 20 floats

    const int prep_n = NA_SHORTS + C_DIM * E_DIM + C_DIM;
    prep_kernel<<<(prep_n + 255) / 256, 256, 0, stream>>>(conv_w, labels, wA, Lt, rnl);
    fused_kernel<<<B_DIM, 256, 0, stream>>>(x, mask, emb, conv_b,
                                            w1, b1, w2, b2, wA, Lt, rnl, out);
}

// Round 5
// 291.151 us; speedup vs baseline: 2.1008x; 1.1973x over previous
//
#include <hip/hip_runtime.h>
#include <math.h>

#define B_DIM 4096
#define S_DIM 200
#define E_DIM 100
#define C_DIM 20
#define K_DIM 51
#define PADW  25
#define V_DIM 50000

typedef _Float16 f16x8 __attribute__((ext_vector_type(8)));
typedef float    f32x4 __attribute__((ext_vector_type(4)));
typedef float    f32x2 __attribute__((ext_vector_type(2)));

// gT: 250 rows x 128B (img0 64B | img1 64B), XOR-swizzled in 16B groups by
// (row & 7) (r3: conflicts -> 0, correctness verified).
#define GT_ROWS   250
#define GT_STRIDE 128
#define GT_BYTES  (GT_ROWS * GT_STRIDE)   // 32000
#define NA_FRAGS  (K_DIM*2*2)    // (k, img, mt)
#define NA_SHORTS (NA_FRAGS*512) // 104448

// workspace layout (bytes); tiers guarded by ws_size at launch (r4 lesson:
// never write workspace beyond ws_size -- 19.4MB unguarded writes killed the
// container).
#define OFF_LT   208896u                  // 2000 floats
#define OFF_RNL  216896u                  // 20 floats
#define OFF_GP   217088u                  // 50000 x 128B packed g rows (6.4 MB)
#define OFF_EW   6617088u                 // 50000 x 256B (64-float rows, 12.8 MB)
#define NEED_G   6617088u
#define NEED_FULL 19417088u

// ---------------------------------------------------------------------------
// Prep 1 (verified): packed-K A-fragments (fp16 split x256, MFMA lane order);
// Lt[e*20+c]; rnl[c].
// ---------------------------------------------------------------------------
__global__ void prep_kernel(const float* __restrict__ conv_w,
                            const float* __restrict__ labels,
                            short* __restrict__ wA,
                            float* __restrict__ Lt,
                            float* __restrict__ rnl) {
    int idx = blockIdx.x * 256 + threadIdx.x;
    if (idx < NA_SHORTS) {
        int frag = idx >> 9;           // ((k*2+img)*2+mt)
        int r    = idx & 511;
        int lane = r >> 3;
        int j    = r & 7;
        int mt   = frag & 1;
        int img  = (frag >> 1) & 1;
        int k    = frag >> 2;
        int o  = mt * 16 + (lane & 15);
        int kc = (lane >> 4) * 8 + j;  // K-col 0..31

        int i = -1, lo = 0;
        if (img == 0) {
            if (kc < 20) { i = kc;      lo = 0; }
            else         { i = kc - 20; lo = 1; }
        } else {
            if (kc < 8)       { i = 12 + kc; lo = 1; }
            else if (kc < 28) { i = kc - 8;  lo = 0; }
        }
        float v = 0.f;
        if (o < C_DIM && i >= 0) v = conv_w[(o * C_DIM + i) * K_DIM + k] * 256.f;
        _Float16 hi  = (_Float16)v;
        _Float16 val = lo ? (_Float16)(v - (float)hi) : hi;
        unsigned short bits;
        __builtin_memcpy(&bits, &val, 2);
        wA[idx] = (short)bits;
    } else if (idx < NA_SHORTS + C_DIM * E_DIM) {
        int t = idx - NA_SHORTS;
        int e = t / C_DIM, c = t % C_DIM;
        Lt[t] = labels[c * E_DIM + e];
    } else if (idx < NA_SHORTS + C_DIM * E_DIM + C_DIM) {
        int c = idx - NA_SHORTS - C_DIM * E_DIM;
        float s = 0.f;
        for (int e = 0; e < E_DIM; ++e) { float v = labels[c * E_DIM + e]; s += v * v; }
        float nn = sqrtf(s);
        rnl[c] = (nn > 0.f) ? 1.f / nn : 0.f;
    }
}

// ---------------------------------------------------------------------------
// Prep 2: per-vocab precompute.  One thread per vocab row v:
//   Gpk[v] = 128B packed split-f16 gT row (byte-identical to the verified r3
//            in-kernel packing), scaled x16.
//   EW[v][u] = dot(emb[v], w1[:,u]) (u<50; rows padded to 64 floats) -- only
//            when DO_EW (full tier).
// Hoists the per-(block,token) cosine GEMM out of the fused kernel.
// ---------------------------------------------------------------------------
template <bool DO_EW>
__global__ void vocab_kernel(const float* __restrict__ emb,
                             const float* __restrict__ w1,
                             const float* __restrict__ Lt,
                             const float* __restrict__ rnl,
                             unsigned* __restrict__ Gpk,
                             float* __restrict__ EW) {
    const int v = blockIdx.x * 256 + threadIdx.x;
    if (v >= V_DIM) return;

    float dacc[C_DIM];
    float accW[E_DIM / 2];
#pragma unroll
    for (int c = 0; c < C_DIM; ++c) dacc[c] = 0.f;
    if (DO_EW) {
#pragma unroll
        for (int u = 0; u < E_DIM / 2; ++u) accW[u] = 0.f;
    }
    float n2 = 0.f;

    const float4* er = (const float4*)(emb + (size_t)v * E_DIM);
    for (int j = 0; j < 25; ++j) {
        const float4 r = er[j];
        n2 += r.x * r.x + r.y * r.y + r.z * r.z + r.w * r.w;
        const float rv[4] = {r.x, r.y, r.z, r.w};
#pragma unroll
        for (int u4 = 0; u4 < 4; ++u4) {
            const int e = j * 4 + u4;
            const float xe = rv[u4];
            const float* Lrow = Lt + e * C_DIM;
#pragma unroll
            for (int c = 0; c < C_DIM; ++c) dacc[c] += xe * Lrow[c];
            if (DO_EW) {
                const float* Wrow = w1 + e * (E_DIM / 2);
#pragma unroll
                for (int u = 0; u < E_DIM / 2; ++u) accW[u] += xe * Wrow[u];
            }
        }
    }

    const float xn    = sqrtf(n2);
    const float rxn16 = (xn > 0.f) ? 16.f / xn : 0.f;

    unsigned short gh[C_DIM], gl[C_DIM];
#pragma unroll
    for (int c = 0; c < C_DIM; ++c) {
        float a = dacc[c] * rnl[c] * rxn16;
        _Float16 h = (_Float16)a;
        _Float16 l = (_Float16)(a - (float)h);
        __builtin_memcpy(&gh[c], &h, 2);
        __builtin_memcpy(&gl[c], &l, 2);
    }
#define PK(a, b) ((unsigned)(a) | ((unsigned)(b) << 16))
    unsigned tv[32];
#pragma unroll
    for (int d = 0; d < 10; ++d) tv[d] = PK(gh[2 * d], gh[2 * d + 1]);
#pragma unroll
    for (int d = 0; d < 6; ++d)  tv[10 + d] = PK(gh[2 * d], gh[2 * d + 1]);
#pragma unroll
    for (int d = 0; d < 4; ++d)  tv[16 + d] = PK(gh[12 + 2 * d], gh[13 + 2 * d]);
#pragma unroll
    for (int d = 0; d < 10; ++d) tv[20 + d] = PK(gl[2 * d], gl[2 * d + 1]);
    tv[30] = 0u; tv[31] = 0u;
#undef PK
    uint4* go = (uint4*)(Gpk + (size_t)v * 32);
#pragma unroll
    for (int g = 0; g < 8; ++g) {
        uint4 q;
        q.x = tv[4 * g + 0]; q.y = tv[4 * g + 1];
        q.z = tv[4 * g + 2]; q.w = tv[4 * g + 3];
        go[g] = q;
    }
    if (DO_EW) {
        float* eo = EW + (size_t)v * 64;
#pragma unroll
        for (int u = 0; u < E_DIM / 2; ++u) eo[u] = accW[u];
    }
}

// ---------------------------------------------------------------------------
// Phase-ring conv (r0 structure, proven spill-free at 64 VGPR + AGPR acc).
// ---------------------------------------------------------------------------
template <int CNT>
__device__ __forceinline__ void conv_tiles(const short* __restrict__ wA,
                                           const char* rowbase,   // gT + (nt0*16+n)*GT_STRIDE
                                           f32x4 (&acc)[4][2],
                                           int lane) {
    const int n = lane & 15;
    const int q = lane >> 4;
#define LDFRAG(k, img, mt) (*(const f16x8*)(wA + (((k) * 2 + (img)) * 2 + (mt)) * 512 + lane * 8))
#pragma unroll
    for (int img = 0; img < 2; ++img) {
#pragma unroll 1
        for (int p = 0; p < 16; ++p) {
            f16x8 a0[4], a1[4];
#pragma unroll
            for (int j = 0; j < 4; ++j) {
                const int k = p + 16 * j;
                if (k < K_DIM) { a0[j] = LDFRAG(k, img, 0); a1[j] = LDFRAG(k, img, 1); }
            }
            const int off = (q * 16 + img * 64) ^ (((n + p) & 7) << 4);
            const char* rp = rowbase + p * GT_STRIDE + off;
            f16x8 ring[CNT + 3];
            const int nd = (p < 3) ? (CNT + 3) : (CNT + 2);
#pragma unroll
            for (int d = 0; d < CNT + 3; ++d) {
                if (d < nd)
                    ring[d] = *(const f16x8*)(rp + d * 16 * GT_STRIDE);
            }
#pragma unroll
            for (int j = 0; j < 4; ++j) {
                if (p + 16 * j < K_DIM) {
#pragma unroll
                    for (int t = 0; t < CNT; ++t) {
                        acc[t][0] = __builtin_amdgcn_mfma_f32_16x16x32_f16(a0[j], ring[t + j], acc[t][0], 0, 0, 0);
                        acc[t][1] = __builtin_amdgcn_mfma_f32_16x16x32_f16(a1[j], ring[t + j], acc[t][1], 0, 0, 0);
                    }
                }
            }
        }
    }
#undef LDFRAG
}

// ---------------------------------------------------------------------------
// Fused kernel, tiered:
//   PRE_G:  phase 1 gathers the precomputed 128B packed g row (vs in-kernel
//           cosine GEMM).
//   USE_EW: pooling in w1-space over precomputed EW rows; MLP layer 1 gone.
// <false,false> is byte-identical in structure to the verified r3 kernel.
// ---------------------------------------------------------------------------
template <bool PRE_G, bool USE_EW>
__launch_bounds__(256, 4)
__global__ void fused_kernel(const int* __restrict__ x,
                             const int* __restrict__ mask,     // bool -> int32
                             const unsigned* __restrict__ Gpk,
                             const float* __restrict__ EW,
                             const float* __restrict__ emb,
                             const float* __restrict__ Lt,
                             const float* __restrict__ rnl,
                             const float* __restrict__ conv_b,
                             const float* __restrict__ w1,
                             const float* __restrict__ b1,
                             const float* __restrict__ w2,
                             const float* __restrict__ b2,
                             const short* __restrict__ wA,
                             float* __restrict__ out) {
    __shared__ __align__(16) char smem[GT_BYTES];   // gT, later aliased
    __shared__ unsigned short toks[S_DIM];

    short* gT   = (short*)smem;
    float* marr = (float*)(smem);            // [0,    800)   after conv
    float* red  = (float*)(smem + 1024);     // cross-wave scratch (8 floats)
    float* bw   = (float*)(smem + 2048);     // [2048, 2848)
    float* zp   = (float*)(smem + 3072);     // 4 x 100 (or 4 x 64)
    float* zsh  = (float*)(smem + 4672);
    float* hsh  = (float*)(smem + 5120);

    const int tid  = threadIdx.x;
    const int b    = blockIdx.x;
    const int lane = tid & 63;
    const int wv   = tid >> 6;
    const int n    = lane & 15;

    // ---- zero gT ----
    {
        float4 z{0.f, 0.f, 0.f, 0.f};
        float4* g4 = (float4*)gT;
        for (int j = tid; j < GT_BYTES / 16; j += 256) g4[j] = z;
    }

    const int s    = tid;
    const bool act = (s < S_DIM);
    int tok = 0, msk = 0;
    if (act) {
        tok = x[b * S_DIM + s];
        msk = mask[b * S_DIM + s];
        toks[s] = (unsigned short)tok;
    }
    __syncthreads();

    // ---- phase 1: packed g row -> swizzled LDS ----
    if (act) {
        const int row = PADW + s;
        const int h8  = row & 7;
        uint4* rw = (uint4*)(smem + row * GT_STRIDE);
        if (PRE_G) {
            const uint4* gp = (const uint4*)(Gpk + (size_t)tok * 32); // one 128B line
            uint4 t0 = gp[0], t1 = gp[1], t2 = gp[2], t3 = gp[3];
            uint4 t4 = gp[4], t5 = gp[5], t6 = gp[6], t7 = gp[7];
            rw[0 ^ h8] = t0; rw[1 ^ h8] = t1; rw[2 ^ h8] = t2; rw[3 ^ h8] = t3;
            rw[4 ^ h8] = t4; rw[5 ^ h8] = t5; rw[6 ^ h8] = t6; rw[7 ^ h8] = t7;
        } else {
            // verified r3 in-kernel cosine path
            f32x2 dacc2[10];
#pragma unroll
            for (int i = 0; i < 10; ++i) dacc2[i] = f32x2{0.f, 0.f};
            float n2 = 0.f;
            const float4* er  = (const float4*)(emb + (size_t)tok * E_DIM);
            const f32x2* Lt2 = (const f32x2*)Lt;
            for (int j = 0; j < 25; ++j) {
                const float4 r = er[j];
                n2 += r.x * r.x + r.y * r.y + r.z * r.z + r.w * r.w;
                const float rv[4] = {r.x, r.y, r.z, r.w};
#pragma unroll
                for (int u = 0; u < 4; ++u) {
                    const f32x2 xe = {rv[u], rv[u]};
                    const f32x2* Lrow = Lt2 + (j * 4 + u) * 10;
#pragma unroll
                    for (int i = 0; i < 10; ++i)
                        dacc2[i] += xe * Lrow[i];
                }
            }
            const float xn    = sqrtf(n2);
            const float rxn16 = (xn > 0.f) ? 16.f / xn : 0.f;

            unsigned short gh[C_DIM], gl[C_DIM];
#pragma unroll
            for (int c = 0; c < C_DIM; ++c) {
                float a = dacc2[c >> 1][c & 1] * rnl[c] * rxn16;
                _Float16 h = (_Float16)a;
                _Float16 l = (_Float16)(a - (float)h);
                __builtin_memcpy(&gh[c], &h, 2);
                __builtin_memcpy(&gl[c], &l, 2);
            }
#define PK(a, b) ((unsigned)(a) | ((unsigned)(b) << 16))
            unsigned tv[32];
#pragma unroll
            for (int d = 0; d < 10; ++d) tv[d] = PK(gh[2 * d], gh[2 * d + 1]);
#pragma unroll
            for (int d = 0; d < 6; ++d)  tv[10 + d] = PK(gh[2 * d], gh[2 * d + 1]);
#pragma unroll
            for (int d = 0; d < 4; ++d)  tv[16 + d] = PK(gh[12 + 2 * d], gh[13 + 2 * d]);
#pragma unroll
            for (int d = 0; d < 10; ++d) tv[20 + d] = PK(gl[2 * d], gl[2 * d + 1]);
            tv[30] = 0u; tv[31] = 0u;
#undef PK
#pragma unroll
            for (int g = 0; g < 8; ++g) {
                uint4 v;
                v.x = tv[4 * g + 0]; v.y = tv[4 * g + 1];
                v.z = tv[4 * g + 2]; v.w = tv[4 * g + 3];
                rw[g ^ h8] = v;
            }
        }
    }
    __syncthreads();

    // ---- conv: waves split the 13 n-tiles (4/3/3/3) ----
    f32x4 acc[4][2];
#pragma unroll
    for (int t = 0; t < 4; ++t) {
        acc[t][0] = f32x4{0.f, 0.f, 0.f, 0.f};
        acc[t][1] = f32x4{0.f, 0.f, 0.f, 0.f};
    }
    const int nt0 = (wv == 0) ? 0 : (1 + wv * 3);      // 0,4,7,10
    const int cnt = (wv == 0) ? 4 : 3;
    const char* rowbase = (const char*)gT + (nt0 * 16 + n) * GT_STRIDE;
    if (wv == 0) conv_tiles<4>(wA, rowbase, acc, lane);
    else         conv_tiles<3>(wA, rowbase, acc, lane);

    __syncthreads();   // gT dead; overlay becomes live

    // ---- epilogue: relu+bias+channel max -> marr[s] (static t indexing) ----
    {
        const int q = lane >> 4;
        const float inv = 1.f / 4096.f;
        float cb0[4], cb1[4];
#pragma unroll
        for (int r = 0; r < 4; ++r) {
            cb0[r] = conv_b[4 * q + r];
            cb1[r] = (q == 0) ? conv_b[16 + r] : 0.f;
        }
#pragma unroll
        for (int t = 0; t < 4; ++t) {
            if (t < cnt) {
                float m = 0.f;   // relu floor
#pragma unroll
                for (int r = 0; r < 4; ++r) m = fmaxf(m, acc[t][0][r] * inv + cb0[r]);
                if (q == 0) {
#pragma unroll
                    for (int r = 0; r < 4; ++r) m = fmaxf(m, acc[t][1][r] * inv + cb1[r]);
                }
                m = fmaxf(m, __shfl_xor(m, 16));
                m = fmaxf(m, __shfl_xor(m, 32));
                const int ss = (nt0 + t) * 16 + n;
                if (q == 0 && ss < S_DIM) marr[ss] = m;
            }
        }
    }
    __syncthreads();

    // ---- softmax over s: wave shuffles + 4-slot cross-wave ----
    {
        float mval = act ? ((msk != 0) ? marr[s] : -1e13f) : -1e30f;
        float lm = mval;
#pragma unroll
        for (int off = 32; off > 0; off >>= 1) lm = fmaxf(lm, __shfl_xor(lm, off));
        if (lane == 0) red[wv] = lm;
        __syncthreads();
        const float gmax = fmaxf(fmaxf(red[0], red[1]), fmaxf(red[2], red[3]));
        const float p = act ? expf(mval - gmax) : 0.f;
        float ps = p;
#pragma unroll
        for (int off = 32; off > 0; off >>= 1) ps += __shfl_xor(ps, off);
        if (lane == 0) red[4 + wv] = ps;
        __syncthreads();
        const float gsum = (red[4] + red[5]) + (red[6] + red[7]);
        if (act) bw[s] = p / gsum;
    }
    __syncthreads();

    if (USE_EW) {
        // ---- pooling in w1-space over EW rows; MLP1 precomputed ----
        {
            const bool pu = (lane < E_DIM / 2);
            float za = 0.f, zb = 0.f;
            const int s0 = wv * 50;
            for (int ss = s0; ss < s0 + 50; ss += 2) {
                const float  w0  = bw[ss];
                const float  w1v = bw[ss + 1];
                const float* r0 = EW + (size_t)toks[ss] * 64;
                const float* r1 = EW + (size_t)toks[ss + 1] * 64;
                if (pu) {
                    za += w0  * r0[lane];
                    zb += w1v * r1[lane];
                }
            }
            if (pu) zp[wv * 64 + lane] = za + zb;
        }
        __syncthreads();
        if (tid < E_DIM / 2) {
            const float h = zp[tid] + zp[64 + tid] + zp[128 + tid] + zp[192 + tid] + b1[tid];
            hsh[tid] = fmaxf(h, 0.f);
        }
        __syncthreads();
    } else {
        // ---- r3 pooling over emb + MLP layer 1 ----
        {
            float za0 = 0.f, zb0 = 0.f, za1 = 0.f, zb1 = 0.f;
            const int s0 = wv * 50;
            for (int ss = s0; ss < s0 + 50; ss += 2) {
                const float  w0  = bw[ss];
                const float  w1v = bw[ss + 1];
                const float* r0 = emb + (size_t)toks[ss] * E_DIM;
                const float* r1 = emb + (size_t)toks[ss + 1] * E_DIM;
                za0 += w0 * r0[lane];
                za1 += w1v * r1[lane];
                if (lane < E_DIM - 64) {
                    zb0 += w0 * r0[64 + lane];
                    zb1 += w1v * r1[64 + lane];
                }
            }
            zp[wv * E_DIM + lane] = za0 + za1;
            if (lane < E_DIM - 64) zp[wv * E_DIM + 64 + lane] = zb0 + zb1;
        }
        __syncthreads();
        if (tid < E_DIM)
            zsh[tid] = zp[tid] + zp[E_DIM + tid] + zp[2 * E_DIM + tid] + zp[3 * E_DIM + tid];
        __syncthreads();
        if (tid < E_DIM / 2) {
            float h = b1[tid];
            for (int e = 0; e < E_DIM; ++e) h += zsh[e] * w1[e * (E_DIM / 2) + tid];
            hsh[tid] = fmaxf(h, 0.f);
        }
        __syncthreads();
    }

    if (tid < C_DIM) {
        float o = b2[tid];
#pragma unroll
        for (int j = 0; j < E_DIM / 2; ++j) o += hsh[j] * w2[j * C_DIM + tid];
        out[b * C_DIM + tid] = o;
    }
}

// ---------------------------------------------------------------------------
extern "C" void kernel_launch(void* const* d_in, const int* in_sizes, int n_in,
                              void* d_out, int out_size, void* d_ws, size_t ws_size,
                              hipStream_t stream) {
    const int*   x      = (const int*)d_in[0];
    const int*   mask   = (const int*)d_in[2];    // bool delivered as int32
    const float* emb    = (const float*)d_in[3];
    const float* labels = (const float*)d_in[4];
    const float* conv_w = (const float*)d_in[5];
    const float* conv_b = (const float*)d_in[6];
    const float* w1     = (const float*)d_in[7];
    const float* b1     = (const float*)d_in[8];
    const float* w2     = (const float*)d_in[9];
    const float* b2     = (const float*)d_in[10];
    float*       out    = (float*)d_out;

    short*    wA  = (short*)d_ws;                         // 208896 B
    float*    Lt  = (float*)((char*)d_ws + OFF_LT);       // 2000 floats
    float*    rnl = (float*)((char*)d_ws + OFF_RNL);      // 20 floats
    unsigned* Gpk = (unsigned*)((char*)d_ws + OFF_GP);    // 6.4 MB (tier >= G)
    float*    EW  = (float*)((char*)d_ws + OFF_EW);       // 12.8 MB (full tier)

    const int prep_n = NA_SHORTS + C_DIM * E_DIM + C_DIM;
    prep_kernel<<<(prep_n + 255) / 256, 256, 0, stream>>>(conv_w, labels, wA, Lt, rnl);

    if (ws_size >= NEED_FULL) {
        vocab_kernel<true><<<(V_DIM + 255) / 256, 256, 0, stream>>>(emb, w1, Lt, rnl, Gpk, EW);
        fused_kernel<true, true><<<B_DIM, 256, 0, stream>>>(
            x, mask, Gpk, EW, emb, Lt, rnl, conv_b, w1, b1, w2, b2, wA, out);
    } else if (ws_size >= NEED_G) {
        vocab_kernel<false><<<(V_DIM + 255) / 256, 256, 0, stream>>>(emb, w1, Lt, rnl, Gpk, EW);
        fused_kernel<true, false><<<B_DIM, 256, 0, stream>>>(
            x, mask, Gpk, EW, emb, Lt, rnl, conv_b, w1, b1, w2, b2, wA, out);
    } else {
        fused_kernel<false, false><<<B_DIM, 256, 0, stream>>>(
            x, mask, Gpk, EW, emb, Lt, rnl, conv_b, w1, b1, w2, b2, wA, out);
    }
}

// Round 6
// 268.022 us; speedup vs baseline: 2.2821x; 1.0863x over previous
//
#include <hip/hip_runtime.h>
#include <math.h>

#define B_DIM 4096
#define S_DIM 200
#define E_DIM 100
#define C_DIM 20
#define K_DIM 51
#define PADW  25
#define V_DIM 50000

typedef _Float16 f16x8 __attribute__((ext_vector_type(8)));
typedef float    f32x4 __attribute__((ext_vector_type(4)));
typedef float    f32x2 __attribute__((ext_vector_type(2)));

// gT: 250 rows x 128B (img0 64B | img1 64B), XOR-swizzled in 16B groups by
// (row & 7) (r3: conflicts -> 0, correctness verified).
#define GT_ROWS   250
#define GT_STRIDE 128
#define GT_BYTES  (GT_ROWS * GT_STRIDE)   // 32000
#define NA_FRAGS  (K_DIM*2*2)    // (k, img, mt)
#define NA_SHORTS (NA_FRAGS*512) // 104448

// workspace layout (bytes); tiers guarded by ws_size at launch (r4 lesson:
// never write workspace beyond ws_size).
#define OFF_LT    208896u                 // 2000 floats
#define OFF_RNL   216896u                 // 20 floats
#define OFF_WC    216976u                 // 100x72 floats (28800 B)
#define OFF_GP    245776u                 // 50000 x 128B packed g rows (6.4 MB)
#define OFF_EW    6645776u                // 50000 x 256B (64-float rows, 12.8 MB)
#define NEED_G    6645776u
#define NEED_FULL 19445776u

// ---------------------------------------------------------------------------
// Prep 1 (verified): packed-K A-fragments (fp16 split x256, MFMA lane order);
// Lt[e*20+c]; rnl[c]; Wc[e*72+o] combined weight columns for vocab_kernel2
// (o<20: labels, 20<=o<70: w1, else 0).
// ---------------------------------------------------------------------------
__global__ void prep_kernel(const float* __restrict__ conv_w,
                            const float* __restrict__ labels,
                            const float* __restrict__ w1,
                            short* __restrict__ wA,
                            float* __restrict__ Lt,
                            float* __restrict__ rnl,
                            float* __restrict__ Wc) {
    int idx = blockIdx.x * 256 + threadIdx.x;
    if (idx < NA_SHORTS) {
        int frag = idx >> 9;           // ((k*2+img)*2+mt)
        int r    = idx & 511;
        int lane = r >> 3;
        int j    = r & 7;
        int mt   = frag & 1;
        int img  = (frag >> 1) & 1;
        int k    = frag >> 2;
        int o  = mt * 16 + (lane & 15);
        int kc = (lane >> 4) * 8 + j;  // K-col 0..31

        int i = -1, lo = 0;
        if (img == 0) {
            if (kc < 20) { i = kc;      lo = 0; }
            else         { i = kc - 20; lo = 1; }
        } else {
            if (kc < 8)       { i = 12 + kc; lo = 1; }
            else if (kc < 28) { i = kc - 8;  lo = 0; }
        }
        float v = 0.f;
        if (o < C_DIM && i >= 0) v = conv_w[(o * C_DIM + i) * K_DIM + k] * 256.f;
        _Float16 hi  = (_Float16)v;
        _Float16 val = lo ? (_Float16)(v - (float)hi) : hi;
        unsigned short bits;
        __builtin_memcpy(&bits, &val, 2);
        wA[idx] = (short)bits;
    } else if (idx < NA_SHORTS + C_DIM * E_DIM) {
        int t = idx - NA_SHORTS;
        int e = t / C_DIM, c = t % C_DIM;
        Lt[t] = labels[c * E_DIM + e];
    } else if (idx < NA_SHORTS + C_DIM * E_DIM + C_DIM) {
        int c = idx - NA_SHORTS - C_DIM * E_DIM;
        float s = 0.f;
        for (int e = 0; e < E_DIM; ++e) { float v = labels[c * E_DIM + e]; s += v * v; }
        float nn = sqrtf(s);
        rnl[c] = (nn > 0.f) ? 1.f / nn : 0.f;
    } else if (idx < NA_SHORTS + C_DIM * E_DIM + C_DIM + E_DIM * 72) {
        int t = idx - NA_SHORTS - C_DIM * E_DIM - C_DIM;
        int e = t / 72, o = t % 72;
        float v = 0.f;
        if (o < C_DIM)      v = labels[o * E_DIM + e];
        else if (o < 70)    v = w1[e * (E_DIM / 2) + (o - C_DIM)];
        Wc[t] = v;
    }
}

// ---------------------------------------------------------------------------
// Prep 2 (rewritten r6): output-parallel vocab precompute.
// r5 post-mortem: one-thread-per-row walked 7000 weight values per thread ->
// ~63us.  Now thread owns ONE output column o (100 weights register-resident,
// loaded once per block) and streams 24 rows through LDS broadcasts.
//   threads: o = tid%72, roff = tid/72 (3 row-phases); tid>=216 idle.
//   o<20  -> raw label dot (scaled by packer);  20<=o<70 -> EW[v][o-20];
//   o==70 -> ||emb||^2;  o==71 -> spare (zero weights).
// 24 packer threads rebuild the byte-identical 128B Gpk line (r5-verified
// packing code).
// ---------------------------------------------------------------------------
#define VCH 24
template <bool DO_EW>
__launch_bounds__(256, 2)
__global__ void vocab_kernel2(const float* __restrict__ emb,
                              const float* __restrict__ Wc,   // [100][72]
                              const float* __restrict__ rnl,
                              unsigned* __restrict__ Gpk,
                              float* __restrict__ EW) {
    __shared__ __align__(16) float embL[VCH][E_DIM];
    __shared__ float dL[VCH][C_DIM];
    __shared__ float n2L[VCH];
    __shared__ float rnlL[C_DIM];

    const int tid = threadIdx.x;
    const int v0  = blockIdx.x * VCH;

    if (tid < C_DIM) rnlL[tid] = rnl[tid];

    // stage 24 emb rows (600 float4, coalesced)
    for (int i = tid; i < VCH * 25; i += 256) {
        const int r = i / 25, c4 = i % 25;
        const int v = v0 + r;
        float4 val{0.f, 0.f, 0.f, 0.f};
        if (v < V_DIM) val = ((const float4*)(emb + (size_t)v * E_DIM))[c4];
        ((float4*)&embL[r][0])[c4] = val;
    }
    __syncthreads();

    const int o    = tid % 72;
    const int roff = tid / 72;
    if (roff < 3) {
        // register-resident weight column (stride-72 gather, L2-hot, once)
        f32x4 wcv[25];
#pragma unroll
        for (int eb = 0; eb < 25; ++eb) {
            f32x4 w;
            w[0] = Wc[(eb * 4 + 0) * 72 + o];
            w[1] = Wc[(eb * 4 + 1) * 72 + o];
            w[2] = Wc[(eb * 4 + 2) * 72 + o];
            w[3] = Wc[(eb * 4 + 3) * 72 + o];
            wcv[eb] = w;
        }
        for (int rr = roff; rr < VCH; rr += 3) {
            const int v = v0 + rr;
            const f32x4* er4 = (const f32x4*)&embL[rr][0];
            f32x4 a4{0.f, 0.f, 0.f, 0.f};
            if (o == 70) {
#pragma unroll
                for (int eb = 0; eb < 25; ++eb) { const f32x4 ev = er4[eb]; a4 += ev * ev; }
                n2L[rr] = a4[0] + a4[1] + a4[2] + a4[3];
            } else if (o < 70) {
#pragma unroll
                for (int eb = 0; eb < 25; ++eb) { const f32x4 ev = er4[eb]; a4 += ev * wcv[eb]; }
                const float acc = a4[0] + a4[1] + a4[2] + a4[3];
                if (o < C_DIM) dL[rr][o] = acc;
                else if (DO_EW && v < V_DIM) EW[(size_t)v * 64 + (o - C_DIM)] = acc;
            }
        }
    }
    __syncthreads();

    // pack phase: one thread per row builds the 128B Gpk line (r5-verified)
    if (tid < VCH) {
        const int v = v0 + tid;
        if (v < V_DIM) {
            const float n2 = n2L[tid];
            const float xn = sqrtf(n2);
            const float rxn16 = (xn > 0.f) ? 16.f / xn : 0.f;
            unsigned short gh[C_DIM], gl[C_DIM];
#pragma unroll
            for (int c = 0; c < C_DIM; ++c) {
                float a = dL[tid][c] * rnlL[c] * rxn16;
                _Float16 h = (_Float16)a;
                _Float16 l = (_Float16)(a - (float)h);
                __builtin_memcpy(&gh[c], &h, 2);
                __builtin_memcpy(&gl[c], &l, 2);
            }
#define PK(a, b) ((unsigned)(a) | ((unsigned)(b) << 16))
            unsigned tv[32];
#pragma unroll
            for (int d = 0; d < 10; ++d) tv[d] = PK(gh[2 * d], gh[2 * d + 1]);
#pragma unroll
            for (int d = 0; d < 6; ++d)  tv[10 + d] = PK(gh[2 * d], gh[2 * d + 1]);
#pragma unroll
            for (int d = 0; d < 4; ++d)  tv[16 + d] = PK(gh[12 + 2 * d], gh[13 + 2 * d]);
#pragma unroll
            for (int d = 0; d < 10; ++d) tv[20 + d] = PK(gl[2 * d], gl[2 * d + 1]);
            tv[30] = 0u; tv[31] = 0u;
#undef PK
            uint4* go = (uint4*)(Gpk + (size_t)v * 32);
#pragma unroll
            for (int g = 0; g < 8; ++g) {
                uint4 q;
                q.x = tv[4 * g + 0]; q.y = tv[4 * g + 1];
                q.z = tv[4 * g + 2]; q.w = tv[4 * g + 3];
                go[g] = q;
            }
        }
    }
}

// ---------------------------------------------------------------------------
// Phase-ring conv (r0 structure, proven spill-free at 64 VGPR + AGPR acc).
// ---------------------------------------------------------------------------
template <int CNT>
__device__ __forceinline__ void conv_tiles(const short* __restrict__ wA,
                                           const char* rowbase,   // gT + (nt0*16+n)*GT_STRIDE
                                           f32x4 (&acc)[4][2],
                                           int lane) {
    const int n = lane & 15;
    const int q = lane >> 4;
#define LDFRAG(k, img, mt) (*(const f16x8*)(wA + (((k) * 2 + (img)) * 2 + (mt)) * 512 + lane * 8))
#pragma unroll
    for (int img = 0; img < 2; ++img) {
#pragma unroll 1
        for (int p = 0; p < 16; ++p) {
            f16x8 a0[4], a1[4];
#pragma unroll
            for (int j = 0; j < 4; ++j) {
                const int k = p + 16 * j;
                if (k < K_DIM) { a0[j] = LDFRAG(k, img, 0); a1[j] = LDFRAG(k, img, 1); }
            }
            const int off = (q * 16 + img * 64) ^ (((n + p) & 7) << 4);
            const char* rp = rowbase + p * GT_STRIDE + off;
            f16x8 ring[CNT + 3];
            const int nd = (p < 3) ? (CNT + 3) : (CNT + 2);
#pragma unroll
            for (int d = 0; d < CNT + 3; ++d) {
                if (d < nd)
                    ring[d] = *(const f16x8*)(rp + d * 16 * GT_STRIDE);
            }
#pragma unroll
            for (int j = 0; j < 4; ++j) {
                if (p + 16 * j < K_DIM) {
#pragma unroll
                    for (int t = 0; t < CNT; ++t) {
                        acc[t][0] = __builtin_amdgcn_mfma_f32_16x16x32_f16(a0[j], ring[t + j], acc[t][0], 0, 0, 0);
                        acc[t][1] = __builtin_amdgcn_mfma_f32_16x16x32_f16(a1[j], ring[t + j], acc[t][1], 0, 0, 0);
                    }
                }
            }
        }
    }
#undef LDFRAG
}

// ---------------------------------------------------------------------------
// Fused kernel, tiered (r5-verified):
//   PRE_G:  phase 1 gathers the precomputed 128B packed g row.
//   USE_EW: pooling in w1-space over precomputed EW rows; MLP layer 1 gone.
// ---------------------------------------------------------------------------
template <bool PRE_G, bool USE_EW>
__launch_bounds__(256, 4)
__global__ void fused_kernel(const int* __restrict__ x,
                             const int* __restrict__ mask,     // bool -> int32
                             const unsigned* __restrict__ Gpk,
                             const float* __restrict__ EW,
                             const float* __restrict__ emb,
                             const float* __restrict__ Lt,
                             const float* __restrict__ rnl,
                             const float* __restrict__ conv_b,
                             const float* __restrict__ w1,
                             const float* __restrict__ b1,
                             const float* __restrict__ w2,
                             const float* __restrict__ b2,
                             const short* __restrict__ wA,
                             float* __restrict__ out) {
    __shared__ __align__(16) char smem[GT_BYTES];   // gT, later aliased
    __shared__ unsigned short toks[S_DIM];

    short* gT   = (short*)smem;
    float* marr = (float*)(smem);            // [0,    800)   after conv
    float* red  = (float*)(smem + 1024);     // cross-wave scratch (8 floats)
    float* bw   = (float*)(smem + 2048);     // [2048, 2848)
    float* zp   = (float*)(smem + 3072);     // 4 x 100 (or 4 x 64)
    float* zsh  = (float*)(smem + 4672);
    float* hsh  = (float*)(smem + 5120);

    const int tid  = threadIdx.x;
    const int b    = blockIdx.x;
    const int lane = tid & 63;
    const int wv   = tid >> 6;
    const int n    = lane & 15;

    // ---- zero only the pad rows [0,25) and [225,250); rows 25..224 are
    // fully written by phase 1 (all 8 swizzled groups per row) ----
    {
        float4 z{0.f, 0.f, 0.f, 0.f};
        for (int i = tid; i < 50 * 8; i += 256) {
            const int rr  = i >> 3;
            const int row = (rr < 25) ? rr : rr + 200;
            ((float4*)(smem + row * GT_STRIDE))[i & 7] = z;
        }
    }

    const int s    = tid;
    const bool act = (s < S_DIM);
    int tok = 0, msk = 0;
    if (act) {
        tok = x[b * S_DIM + s];
        msk = mask[b * S_DIM + s];
        toks[s] = (unsigned short)tok;
    }
    __syncthreads();

    // ---- phase 1: packed g row -> swizzled LDS ----
    if (act) {
        const int row = PADW + s;
        const int h8  = row & 7;
        uint4* rw = (uint4*)(smem + row * GT_STRIDE);
        if (PRE_G) {
            const uint4* gp = (const uint4*)(Gpk + (size_t)tok * 32); // one 128B line
            uint4 t0 = gp[0], t1 = gp[1], t2 = gp[2], t3 = gp[3];
            uint4 t4 = gp[4], t5 = gp[5], t6 = gp[6], t7 = gp[7];
            rw[0 ^ h8] = t0; rw[1 ^ h8] = t1; rw[2 ^ h8] = t2; rw[3 ^ h8] = t3;
            rw[4 ^ h8] = t4; rw[5 ^ h8] = t5; rw[6 ^ h8] = t6; rw[7 ^ h8] = t7;
        } else {
            // verified r3 in-kernel cosine path
            f32x2 dacc2[10];
#pragma unroll
            for (int i = 0; i < 10; ++i) dacc2[i] = f32x2{0.f, 0.f};
            float n2 = 0.f;
            const float4* er  = (const float4*)(emb + (size_t)tok * E_DIM);
            const f32x2* Lt2 = (const f32x2*)Lt;
            for (int j = 0; j < 25; ++j) {
                const float4 r = er[j];
                n2 += r.x * r.x + r.y * r.y + r.z * r.z + r.w * r.w;
                const float rv[4] = {r.x, r.y, r.z, r.w};
#pragma unroll
                for (int u = 0; u < 4; ++u) {
                    const f32x2 xe = {rv[u], rv[u]};
                    const f32x2* Lrow = Lt2 + (j * 4 + u) * 10;
#pragma unroll
                    for (int i = 0; i < 10; ++i)
                        dacc2[i] += xe * Lrow[i];
                }
            }
            const float xn    = sqrtf(n2);
            const float rxn16 = (xn > 0.f) ? 16.f / xn : 0.f;

            unsigned short gh[C_DIM], gl[C_DIM];
#pragma unroll
            for (int c = 0; c < C_DIM; ++c) {
                float a = dacc2[c >> 1][c & 1] * rnl[c] * rxn16;
                _Float16 h = (_Float16)a;
                _Float16 l = (_Float16)(a - (float)h);
                __builtin_memcpy(&gh[c], &h, 2);
                __builtin_memcpy(&gl[c], &l, 2);
            }
#define PK(a, b) ((unsigned)(a) | ((unsigned)(b) << 16))
            unsigned tv[32];
#pragma unroll
            for (int d = 0; d < 10; ++d) tv[d] = PK(gh[2 * d], gh[2 * d + 1]);
#pragma unroll
            for (int d = 0; d < 6; ++d)  tv[10 + d] = PK(gh[2 * d], gh[2 * d + 1]);
#pragma unroll
            for (int d = 0; d < 4; ++d)  tv[16 + d] = PK(gh[12 + 2 * d], gh[13 + 2 * d]);
#pragma unroll
            for (int d = 0; d < 10; ++d) tv[20 + d] = PK(gl[2 * d], gl[2 * d + 1]);
            tv[30] = 0u; tv[31] = 0u;
#undef PK
#pragma unroll
            for (int g = 0; g < 8; ++g) {
                uint4 v;
                v.x = tv[4 * g + 0]; v.y = tv[4 * g + 1];
                v.z = tv[4 * g + 2]; v.w = tv[4 * g + 3];
                rw[g ^ h8] = v;
            }
        }
    }
    __syncthreads();

    // ---- conv: waves split the 13 n-tiles (4/3/3/3) ----
    f32x4 acc[4][2];
#pragma unroll
    for (int t = 0; t < 4; ++t) {
        acc[t][0] = f32x4{0.f, 0.f, 0.f, 0.f};
        acc[t][1] = f32x4{0.f, 0.f, 0.f, 0.f};
    }
    const int nt0 = (wv == 0) ? 0 : (1 + wv * 3);      // 0,4,7,10
    const int cnt = (wv == 0) ? 4 : 3;
    const char* rowbase = (const char*)gT + (nt0 * 16 + n) * GT_STRIDE;
    if (wv == 0) conv_tiles<4>(wA, rowbase, acc, lane);
    else         conv_tiles<3>(wA, rowbase, acc, lane);

    __syncthreads();   // gT dead; overlay becomes live

    // ---- epilogue: relu+bias+channel max -> marr[s] (static t indexing) ----
    {
        const int q = lane >> 4;
        const float inv = 1.f / 4096.f;
        float cb0[4], cb1[4];
#pragma unroll
        for (int r = 0; r < 4; ++r) {
            cb0[r] = conv_b[4 * q + r];
            cb1[r] = (q == 0) ? conv_b[16 + r] : 0.f;
        }
#pragma unroll
        for (int t = 0; t < 4; ++t) {
            if (t < cnt) {
                float m = 0.f;   // relu floor
#pragma unroll
                for (int r = 0; r < 4; ++r) m = fmaxf(m, acc[t][0][r] * inv + cb0[r]);
                if (q == 0) {
#pragma unroll
                    for (int r = 0; r < 4; ++r) m = fmaxf(m, acc[t][1][r] * inv + cb1[r]);
                }
                m = fmaxf(m, __shfl_xor(m, 16));
                m = fmaxf(m, __shfl_xor(m, 32));
                const int ss = (nt0 + t) * 16 + n;
                if (q == 0 && ss < S_DIM) marr[ss] = m;
            }
        }
    }
    __syncthreads();

    // ---- softmax over s: wave shuffles + 4-slot cross-wave ----
    {
        float mval = act ? ((msk != 0) ? marr[s] : -1e13f) : -1e30f;
        float lm = mval;
#pragma unroll
        for (int off = 32; off > 0; off >>= 1) lm = fmaxf(lm, __shfl_xor(lm, off));
        if (lane == 0) red[wv] = lm;
        __syncthreads();
        const float gmax = fmaxf(fmaxf(red[0], red[1]), fmaxf(red[2], red[3]));
        const float p = act ? expf(mval - gmax) : 0.f;
        float ps = p;
#pragma unroll
        for (int off = 32; off > 0; off >>= 1) ps += __shfl_xor(ps, off);
        if (lane == 0) red[4 + wv] = ps;
        __syncthreads();
        const float gsum = (red[4] + red[5]) + (red[6] + red[7]);
        if (act) bw[s] = p / gsum;
    }
    __syncthreads();

    if (USE_EW) {
        // ---- pooling in w1-space over EW rows; MLP1 precomputed ----
        {
            const bool pu = (lane < E_DIM / 2);
            float za = 0.f, zb = 0.f;
            const int s0 = wv * 50;
            for (int ss = s0; ss < s0 + 50; ss += 2) {
                const float  w0  = bw[ss];
                const float  w1v = bw[ss + 1];
                const float* r0 = EW + (size_t)toks[ss] * 64;
                const float* r1 = EW + (size_t)toks[ss + 1] * 64;
                if (pu) {
                    za += w0  * r0[lane];
                    zb += w1v * r1[lane];
                }
            }
            if (pu) zp[wv * 64 + lane] = za + zb;
        }
        __syncthreads();
        if (tid < E_DIM / 2) {
            const float h = zp[tid] + zp[64 + tid] + zp[128 + tid] + zp[192 + tid] + b1[tid];
            hsh[tid] = fmaxf(h, 0.f);
        }
        __syncthreads();
    } else {
        // ---- r3 pooling over emb + MLP layer 1 ----
        {
            float za0 = 0.f, zb0 = 0.f, za1 = 0.f, zb1 = 0.f;
            const int s0 = wv * 50;
            for (int ss = s0; ss < s0 + 50; ss += 2) {
                const float  w0  = bw[ss];
                const float  w1v = bw[ss + 1];
                const float* r0 = emb + (size_t)toks[ss] * E_DIM;
                const float* r1 = emb + (size_t)toks[ss + 1] * E_DIM;
                za0 += w0 * r0[lane];
                za1 += w1v * r1[lane];
                if (lane < E_DIM - 64) {
                    zb0 += w0 * r0[64 + lane];
                    zb1 += w1v * r1[64 + lane];
                }
            }
            zp[wv * E_DIM + lane] = za0 + za1;
            if (lane < E_DIM - 64) zp[wv * E_DIM + 64 + lane] = zb0 + zb1;
        }
        __syncthreads();
        if (tid < E_DIM)
            zsh[tid] = zp[tid] + zp[E_DIM + tid] + zp[2 * E_DIM + tid] + zp[3 * E_DIM + tid];
        __syncthreads();
        if (tid < E_DIM / 2) {
            float h = b1[tid];
            for (int e = 0; e < E_DIM; ++e) h += zsh[e] * w1[e * (E_DIM / 2) + tid];
            hsh[tid] = fmaxf(h, 0.f);
        }
        __syncthreads();
    }

    if (tid < C_DIM) {
        float o = b2[tid];
#pragma unroll
        for (int j = 0; j < E_DIM / 2; ++j) o += hsh[j] * w2[j * C_DIM + tid];
        out[b * C_DIM + tid] = o;
    }
}

// ---------------------------------------------------------------------------
extern "C" void kernel_launch(void* const* d_in, const int* in_sizes, int n_in,
                              void* d_out, int out_size, void* d_ws, size_t ws_size,
                              hipStream_t stream) {
    const int*   x      = (const int*)d_in[0];
    const int*   mask   = (const int*)d_in[2];    // bool delivered as int32
    const float* emb    = (const float*)d_in[3];
    const float* labels = (const float*)d_in[4];
    const float* conv_w = (const float*)d_in[5];
    const float* conv_b = (const float*)d_in[6];
    const float* w1     = (const float*)d_in[7];
    const float* b1     = (const float*)d_in[8];
    const float* w2     = (const float*)d_in[9];
    const float* b2     = (const float*)d_in[10];
    float*       out    = (float*)d_out;

    short*    wA  = (short*)d_ws;                         // 208896 B
    float*    Lt  = (float*)((char*)d_ws + OFF_LT);
    float*    rnl = (float*)((char*)d_ws + OFF_RNL);
    float*    Wc  = (float*)((char*)d_ws + OFF_WC);
    unsigned* Gpk = (unsigned*)((char*)d_ws + OFF_GP);
    float*    EW  = (float*)((char*)d_ws + OFF_EW);

    const int prep_n = NA_SHORTS + C_DIM * E_DIM + C_DIM + E_DIM * 72;
    prep_kernel<<<(prep_n + 255) / 256, 256, 0, stream>>>(conv_w, labels, w1,
                                                          wA, Lt, rnl, Wc);

    const int vg = (V_DIM + VCH - 1) / VCH;
    if (ws_size >= NEED_FULL) {
        vocab_kernel2<true><<<vg, 256, 0, stream>>>(emb, Wc, rnl, Gpk, EW);
        fused_kernel<true, true><<<B_DIM, 256, 0, stream>>>(
            x, mask, Gpk, EW, emb, Lt, rnl, conv_b, w1, b1, w2, b2, wA, out);
    } else if (ws_size >= NEED_G) {
        vocab_kernel2<false><<<vg, 256, 0, stream>>>(emb, Wc, rnl, Gpk, EW);
        fused_kernel<true, false><<<B_DIM, 256, 0, stream>>>(
            x, mask, Gpk, EW, emb, Lt, rnl, conv_b, w1, b1, w2, b2, wA, out);
    } else {
        fused_kernel<false, false><<<B_DIM, 256, 0, stream>>>(
            x, mask, Gpk, EW, emb, Lt, rnl, conv_b, w1, b1, w2, b2, wA, out);
    }
}